// Round 4
// baseline (30098.465 us; speedup 1.0000x reference)
//
#include <hip/hip_runtime.h>

// ---------------------------------------------------------------------------
// Seq2SeqAttentionDecoder — round 4: persistent recurrence v2
//  Round-3 counters: k_persist 21.9ms, VALUBusy 8%, Occ 12.4%, 100 GB/s eff.
//  -> latency-starved, not BW/VALU. Fixes:
//   * 512 blocks (2/CU, 8 waves/CU; __launch_bounds__(256,2) caps VGPRs so
//     >=2 blocks/CU always resident -> barrier-safe)
//   * keys/enc pre-converted bf16, read as u16x8 (16B/lane, was scalar 4B)
//   * 4-way K-split per gate output (192 weight loads/thread, was 384)
//   * q-projection fused into P5 as split-K partials -> 4 barriers/step
//  Weight slices stay XCD-L2-resident: block bid -> (b=bid>>4, slice=bid&15),
//  slice s lives on XCD s%8 every step (bid%8 dispatch round-robin).
// ---------------------------------------------------------------------------

#define BB 32
#define TT 64
#define SS 128
#define HH 1024
#define EE 512
#define VV 32000
#define H3 3072
#define NEGV (-1000000.0f)
#define NB 512          // persistent grid blocks

typedef __attribute__((ext_vector_type(8))) unsigned short u16x8;

__device__ __forceinline__ unsigned short f2bf(float f) {
  unsigned int u = __builtin_bit_cast(unsigned int, f);
  unsigned int r = (u + 0x7FFFu + ((u >> 16) & 1u)) >> 16;   // RNE
  return (unsigned short)r;
}
__device__ __forceinline__ float bfu(unsigned short u) {
  return __builtin_bit_cast(float, (unsigned int)u << 16);
}
__device__ __forceinline__ float sigm(float x) {
  return 1.f / (1.f + __expf(-x));
}
__device__ __forceinline__ float tanhfast(float x) {
  float ax = fabsf(x);
  float e = __expf(2.f * ax);
  float th = 1.f - 2.f / (e + 1.f);
  return copysignf(th, x);
}
__device__ __forceinline__ void fma8(float& acc, u16x8 w, float4 x0, float4 x1) {
  acc = fmaf(bfu(w[0]), x0.x, acc); acc = fmaf(bfu(w[1]), x0.y, acc);
  acc = fmaf(bfu(w[2]), x0.z, acc); acc = fmaf(bfu(w[3]), x0.w, acc);
  acc = fmaf(bfu(w[4]), x1.x, acc); acc = fmaf(bfu(w[5]), x1.y, acc);
  acc = fmaf(bfu(w[6]), x1.z, acc); acc = fmaf(bfu(w[7]), x1.w, acc);
}

// ---------- init: h0A = hidden[0], zero barrier counter ----------
__global__ __launch_bounds__(256) void k_init(const float* __restrict__ hid,
                                              float* __restrict__ h0A,
                                              unsigned* __restrict__ bar) {
  int i = blockIdx.x * 256 + threadIdx.x;
  if (i < BB * HH) h0A[i] = hid[i];
  if (i == 0) *bar = 0u;
}

// ---------- gather xs[r=t*B+b][e] = emb[X[b][t]][e]  (fp32) ----------
__global__ __launch_bounds__(256) void k_gather(const int* __restrict__ X,
                                                const float* __restrict__ emb,
                                                float* __restrict__ xs) {
  int idx = blockIdx.x * 256 + threadIdx.x;
  int r = idx >> 7, c4 = (idx & 127) << 2;
  int td = r >> 5, b = r & 31;
  int tok = X[b * TT + td];
  *(float4*)(xs + (size_t)r * EE + c4) =
      *(const float4*)(emb + (size_t)tok * EE + c4);
}

// ---------- fp32 -> packed bf16 (grid = rows) ----------
__global__ __launch_bounds__(256) void k_conv(const float* __restrict__ src,
                                              unsigned short* __restrict__ dst,
                                              int cols4, int ld) {
  int r = blockIdx.x;
  for (int c = threadIdx.x; c < cols4; c += 256) {
    float4 v = *(const float4*)(src + (size_t)r * ld + (size_t)c * 4);
    ushort4 o;
    o.x = f2bf(v.x); o.y = f2bf(v.y); o.z = f2bf(v.z); o.w = f2bf(v.w);
    *(ushort4*)(dst + (size_t)r * cols4 * 4 + (size_t)c * 4) = o;
  }
}

// ---------- fp32 tiled GEMM (proven): C = A @ W^T (+bias), opt bf16 out ----
__global__ __launch_bounds__(256) void k_gemm_tiled(
    const float* __restrict__ A, int lda,
    const float* __restrict__ W, int ldw,
    const float* __restrict__ bias,
    float* __restrict__ C, int M, int N, int K, int permuteBT, int outBF16) {
  __shared__ float As[16][132];
  __shared__ float Ws[16][132];
  const int m0 = blockIdx.y * 128, n0 = blockIdx.x * 128;
  const int t = threadIdx.x;
  const int tm = t >> 4, tn = t & 15;
  float acc[8][8] = {};
  for (int k0 = 0; k0 < K; k0 += 16) {
#pragma unroll
    for (int qq = 0; qq < 2; ++qq) {
      int f = t * 2 + qq;
      int row = f >> 2, c4 = (f & 3) << 2;
      float4 va = *(const float4*)(A + (size_t)(m0 + row) * lda + k0 + c4);
      As[c4 + 0][row] = va.x; As[c4 + 1][row] = va.y;
      As[c4 + 2][row] = va.z; As[c4 + 3][row] = va.w;
      float4 vw = *(const float4*)(W + (size_t)(n0 + row) * ldw + k0 + c4);
      Ws[c4 + 0][row] = vw.x; Ws[c4 + 1][row] = vw.y;
      Ws[c4 + 2][row] = vw.z; Ws[c4 + 3][row] = vw.w;
    }
    __syncthreads();
#pragma unroll
    for (int k = 0; k < 16; ++k) {
      float a[8], w[8];
      *(float4*)&a[0] = *(const float4*)&As[k][tm * 8];
      *(float4*)&a[4] = *(const float4*)&As[k][tm * 8 + 4];
      *(float4*)&w[0] = *(const float4*)&Ws[k][tn * 8];
      *(float4*)&w[4] = *(const float4*)&Ws[k][tn * 8 + 4];
#pragma unroll
      for (int i = 0; i < 8; ++i)
#pragma unroll
        for (int j = 0; j < 8; ++j) acc[i][j] = fmaf(a[i], w[j], acc[i][j]);
    }
    __syncthreads();
  }
#pragma unroll
  for (int i = 0; i < 8; ++i) {
    int m = m0 + tm * 8 + i;
    size_t rowoff = permuteBT ? ((size_t)((m & 31) * TT + (m >> 5))) * N
                              : (size_t)m * N;
#pragma unroll
    for (int jj = 0; jj < 2; ++jj) {
      int n = n0 + tn * 8 + jj * 4;
      float4 v;
      v.x = acc[i][jj * 4 + 0]; v.y = acc[i][jj * 4 + 1];
      v.z = acc[i][jj * 4 + 2]; v.w = acc[i][jj * 4 + 3];
      if (bias) { v.x += bias[n]; v.y += bias[n + 1];
                  v.z += bias[n + 2]; v.w += bias[n + 3]; }
      if (outBF16) {
        ushort4 o;
        o.x = f2bf(v.x); o.y = f2bf(v.y); o.z = f2bf(v.z); o.w = f2bf(v.w);
        *(ushort4*)((unsigned short*)C + rowoff + n) = o;
      } else {
        *(float4*)(C + rowoff + n) = v;
      }
    }
  }
}

// ---------- gates + GRU for one layer (4 threads per output) ----------
// Block owns (batch b, 64-row n-slice sl). xg/hg: [B][H] fp32 global inputs
// (ih-side, hh-side=h_prev). wi/wh: bf16 [3][1024][1024] gate-major.
__device__ __forceinline__ void gru_phase(
    int b, int sl, int t, float* shm,
    const float* __restrict__ xg, const float* __restrict__ hg,
    const unsigned short* __restrict__ wi, const unsigned short* __restrict__ wh,
    const unsigned short* __restrict__ gixrow, const float* __restrict__ bih,
    const float* __restrict__ bhh, float* __restrict__ hdst, float* stash) {
  ((float4*)shm)[t]       = *(const float4*)(xg + b * HH + t * 4);
  ((float4*)shm)[256 + t] = *(const float4*)(hg + b * HH + t * 4);
  __syncthreads();
  const int nl = t >> 2, q4 = t & 3;
  const int n = sl * 64 + nl;
  const int k0 = q4 * 256;
  float air = 0, aiz = 0, ain = 0, ahr = 0, ahz = 0, ahn = 0;
  const unsigned short* wr = wi + (size_t)n * HH + k0;
  const unsigned short* hr = wh + (size_t)n * HH + k0;
#pragma unroll 2
  for (int j = 0; j < 32; ++j) {
    float4 x0 = *(const float4*)&shm[k0 + j * 8];
    float4 x1 = *(const float4*)&shm[k0 + j * 8 + 4];
    float4 y0 = *(const float4*)&shm[1024 + k0 + j * 8];
    float4 y1 = *(const float4*)&shm[1024 + k0 + j * 8 + 4];
    fma8(air, *(const u16x8*)(wr + j * 8),           x0, x1);
    fma8(aiz, *(const u16x8*)(wr + 1048576 + j * 8), x0, x1);
    fma8(ain, *(const u16x8*)(wr + 2097152 + j * 8), x0, x1);
    fma8(ahr, *(const u16x8*)(hr + j * 8),           y0, y1);
    fma8(ahz, *(const u16x8*)(hr + 1048576 + j * 8), y0, y1);
    fma8(ahn, *(const u16x8*)(hr + 2097152 + j * 8), y0, y1);
  }
  air += __shfl_xor(air, 1); air += __shfl_xor(air, 2);
  aiz += __shfl_xor(aiz, 1); aiz += __shfl_xor(aiz, 2);
  ain += __shfl_xor(ain, 1); ain += __shfl_xor(ain, 2);
  ahr += __shfl_xor(ahr, 1); ahr += __shfl_xor(ahr, 2);
  ahz += __shfl_xor(ahz, 1); ahz += __shfl_xor(ahz, 2);
  ahn += __shfl_xor(ahn, 1); ahn += __shfl_xor(ahn, 2);
  if (q4 == 0) {
    float gr = air, gz = aiz, gn = ain;
    if (gixrow) {
      gr += bfu(gixrow[n]); gz += bfu(gixrow[HH + n]);
      gn += bfu(gixrow[2 * HH + n]);
    }
    if (bih) { gr += bih[n]; gz += bih[HH + n]; gn += bih[2 * HH + n]; }
    float h_r = ahr + bhh[n], h_z = ahz + bhh[HH + n], h_n = ahn + bhh[2 * HH + n];
    float r = sigm(gr + h_r);
    float z = sigm(gz + h_z);
    float nn = tanhfast(gn + r * h_n);
    float hv = (1.f - z) * nn + z * shm[1024 + n];
    hdst[b * HH + n] = hv;
    if (stash) stash[nl] = hv;
  }
}

// ---------- qpart[sl][b][nq] += (x-slice 64) @ Wq cols ----------
// x staged at shm[xoff..xoff+64). Each thread: 4 consecutive nq.
__device__ __forceinline__ void qpart_phase(
    int b, int sl, int t, const float* shm, int xoff,
    const unsigned short* __restrict__ wqb, float* __restrict__ qpart) {
  const int nq = t * 4;
  const unsigned short* w0 = wqb + (size_t)nq * HH + sl * 64;
  float a0 = 0, a1 = 0, a2 = 0, a3 = 0;
#pragma unroll
  for (int k8 = 0; k8 < 8; ++k8) {
    float4 x0 = *(const float4*)&shm[xoff + k8 * 8];
    float4 x1 = *(const float4*)&shm[xoff + k8 * 8 + 4];
    fma8(a0, *(const u16x8*)(w0 + k8 * 8),          x0, x1);
    fma8(a1, *(const u16x8*)(w0 + HH + k8 * 8),     x0, x1);
    fma8(a2, *(const u16x8*)(w0 + 2 * HH + k8 * 8), x0, x1);
    fma8(a3, *(const u16x8*)(w0 + 3 * HH + k8 * 8), x0, x1);
  }
  float4 o; o.x = a0; o.y = a1; o.z = a2; o.w = a3;
  *(float4*)(qpart + ((size_t)sl * BB + b) * HH + nq) = o;
}

// ---------- the persistent recurrence kernel ----------
__global__ __launch_bounds__(256, 2) void k_persist(
    const unsigned short* __restrict__ keysb,
    const unsigned short* __restrict__ encb,
    const unsigned short* __restrict__ gi0xb,
    const unsigned short* __restrict__ wqb,
    const unsigned short* __restrict__ wi0, const unsigned short* __restrict__ wh0,
    const unsigned short* __restrict__ wi1, const unsigned short* __restrict__ wh1,
    const float* __restrict__ wv, const int* __restrict__ vlen,
    const float* __restrict__ hid1,
    const float* __restrict__ bhh0, const float* __restrict__ bih1,
    const float* __restrict__ bhh1,
    float* __restrict__ qpart, float* __restrict__ scores,
    float* __restrict__ ctx,
    float* __restrict__ h0A, float* __restrict__ h0B, float* __restrict__ outs,
    unsigned* __restrict__ bar) {
  __shared__ float shm[2304];
  const int bid = blockIdx.x, t = threadIdx.x;
  const int b = bid >> 4, sl = bid & 15;
  unsigned ep = 0;

#define GBAR() do { ++ep; __syncthreads();                                     \
    if (t == 0) {                                                              \
      __threadfence();                                                         \
      __hip_atomic_fetch_add(bar, 1u, __ATOMIC_RELAXED,                        \
                             __HIP_MEMORY_SCOPE_AGENT);                        \
      while (__hip_atomic_load(bar, __ATOMIC_RELAXED,                          \
                               __HIP_MEMORY_SCOPE_AGENT) < ep * (unsigned)NB)  \
        __builtin_amdgcn_s_sleep(1);                                           \
      __threadfence();                                                         \
    }                                                                          \
    __syncthreads(); } while (0)

  // ---- P0 (once): qpart from initial h1 = hid1 ----
  if (t < 16)
    *(float4*)&shm[t * 4] = *(const float4*)(hid1 + b * HH + sl * 64 + t * 4);
  __syncthreads();
  qpart_phase(b, sl, t, shm, 0, wqb, qpart);
  GBAR();

  for (int td = 0; td < TT; ++td) {
    const float* h1old = td ? outs + (size_t)(td - 1) * BB * HH : hid1;
    const float* h0old = (td & 1) ? h0B : h0A;
    float*       h0new = (td & 1) ? h0A : h0B;

    // ---- P2: scores[b][s] = sum_h tanh(q+keys)*wv, masked ----
    {
      float4 a = {0, 0, 0, 0};
#pragma unroll
      for (int p = 0; p < 16; ++p) {
        float4 v = *(const float4*)(qpart + ((size_t)p * BB + b) * HH + t * 4);
        a.x += v.x; a.y += v.y; a.z += v.z; a.w += v.w;
      }
      *(float4*)&shm[t * 4] = a;                         // qs
      *(float4*)&shm[1024 + t * 4] = *(const float4*)(wv + t * 4);  // wv
      __syncthreads();
      const int sloc = t >> 5, g = t & 31;
      const int s = sl * 8 + sloc;
      const unsigned short* kr = keysb + ((size_t)(b * SS + s)) * HH + g * 8;
      float acc = 0;
#pragma unroll
      for (int kk = 0; kk < 4; ++kk) {
        u16x8 kv = *(const u16x8*)(kr + kk * 256);
        int h = kk * 256 + g * 8;
#pragma unroll
        for (int i = 0; i < 8; ++i)
          acc = fmaf(tanhfast(shm[h + i] + bfu(kv[i])), shm[1024 + h + i], acc);
      }
      acc += __shfl_xor(acc, 1); acc += __shfl_xor(acc, 2);
      acc += __shfl_xor(acc, 4); acc += __shfl_xor(acc, 8);
      acc += __shfl_xor(acc, 16);
      if (g == 0) scores[b * SS + s] = (s < vlen[b]) ? acc : NEGV;
    }
    GBAR();

    // ---- P3: softmax + ctx (block covers 64 c-columns of batch b) ----
    {
      if (t < SS) shm[t] = scores[b * SS + t];
      __syncthreads();
      float mx = shm[0];
#pragma unroll 8
      for (int s = 1; s < SS; ++s) mx = fmaxf(mx, shm[s]);
      float p = (t < SS) ? __expf(shm[t] - mx) : 0.f;
      __syncthreads();
      if (t < SS) shm[t] = p;
      __syncthreads();
      float sum = 0;
#pragma unroll 8
      for (int s = 0; s < SS; ++s) sum += shm[s];
      const float inv = 1.f / sum;
      const int c8 = t & 7, sg = t >> 3;
      const int c = sl * 64 + c8 * 8;
      float a[8] = {};
#pragma unroll
      for (int si = 0; si < 4; ++si) {
        int s = sg * 4 + si;
        u16x8 e = *(const u16x8*)(encb + ((size_t)(b * SS + s)) * HH + c);
        float p2 = shm[s];
#pragma unroll
        for (int i = 0; i < 8; ++i) a[i] = fmaf(p2, bfu(e[i]), a[i]);
      }
#pragma unroll
      for (int i = 0; i < 8; ++i) shm[128 + sg * 64 + c8 * 8 + i] = a[i];
      __syncthreads();
      if (t < 64) {
        float s2 = 0;
#pragma unroll
        for (int g2 = 0; g2 < 32; ++g2) s2 += shm[128 + g2 * 64 + t];
        ctx[b * HH + sl * 64 + t] = s2 * inv;
      }
    }
    GBAR();

    // ---- P4: layer-0 gates + GRU -> h0new ----
    gru_phase(b, sl, t, shm, ctx, h0old, wi0, wh0,
              gi0xb + ((size_t)td * BB + b) * H3, nullptr, bhh0, h0new, nullptr);
    GBAR();

    // ---- P5: layer-1 gates + GRU -> outs[td]; fused qpart for next step ----
    gru_phase(b, sl, t, shm, h0new, h1old, wi1, wh1,
              nullptr, bih1, bhh1, outs + (size_t)td * BB * HH, &shm[2048]);
    if (td < TT - 1) {
      __syncthreads();
      qpart_phase(b, sl, t, shm, 2048, wqb, qpart);
    }
    GBAR();
  }
#undef GBAR
}

// ---------------------------------------------------------------------------
extern "C" void kernel_launch(void* const* d_in, const int* in_sizes, int n_in,
                              void* d_out, int out_size, void* d_ws,
                              size_t ws_size, hipStream_t stream) {
  const int*   X    = (const int*)  d_in[0];
  const float* enc  = (const float*)d_in[1];
  const float* hid  = (const float*)d_in[2];
  const int*   vlen = (const int*)  d_in[3];
  const float* emb  = (const float*)d_in[4];
  const float* Wq   = (const float*)d_in[5];
  const float* Wk   = (const float*)d_in[6];
  const float* wv   = (const float*)d_in[7];
  const float* Wih0 = (const float*)d_in[8];
  const float* Whh0 = (const float*)d_in[9];
  const float* bih0 = (const float*)d_in[10];
  const float* bhh0 = (const float*)d_in[11];
  const float* Wih1 = (const float*)d_in[12];
  const float* Whh1 = (const float*)d_in[13];
  const float* bih1 = (const float*)d_in[14];
  const float* bhh1 = (const float*)d_in[15];
  const float* Wout = (const float*)d_in[16];
  const float* bout = (const float*)d_in[17];
  float* out = (float*)d_out;

  // ---- workspace (float offsets), total ~17.40M f = 69.6 MB ----
  float* ws = (float*)d_ws;
  unsigned short* wi0b  = (unsigned short*)ws;                 // [3][1024][1024]
  unsigned short* wh0b  = wi0b + (size_t)3145728;
  unsigned short* wi1b  = (unsigned short*)(ws + 3145728);
  unsigned short* wh1b  = wi1b + (size_t)3145728;
  float*          outs  = ws + 6291456;                        // 2,097,152
  float*          xs    = ws + 8388608;                        // 1,048,576 (dead after gi0x)
  unsigned short* wqb   = (unsigned short*)xs;                 // alias after
  unsigned short* gi0xb = (unsigned short*)(ws + 9437184);     // 3,145,728 f worth
  unsigned short* keysb = (unsigned short*)(ws + 12582912);    // 2,097,152 f worth
  unsigned short* encb  = (unsigned short*)(ws + 14680064);    // 2,097,152 f worth
  float*          qpart = ws + 16777216;                       //   524,288
  float*          h0A   = ws + 17301504;                       //    32,768
  float*          h0B   = ws + 17334272;                       //    32,768
  float*          ctx   = ws + 17367040;                       //    32,768
  float*          scores= ws + 17399808;                       //     4,096
  unsigned*       bar   = (unsigned*)(ws + 17403904);

  k_init<<<128, 256, 0, stream>>>(hid, h0A, bar);
  k_gather<<<1024, 256, 0, stream>>>(X, emb, xs);
  // keysb = bf16(enc @ Wk^T)
  k_gemm_tiled<<<dim3(8, 32), 256, 0, stream>>>(enc, HH, Wk, HH, nullptr,
                                                (float*)keysb, BB * SS, HH, HH,
                                                0, 1);
  k_conv<<<4096, 256, 0, stream>>>(enc, encb, 256, HH);
  // gi0xb = bf16(xs @ W_ih0[:,H:]^T + b_ih0)
  k_gemm_tiled<<<dim3(24, 16), 256, 0, stream>>>(xs, EE, Wih0 + HH, HH + EE,
                                                 bih0, (float*)gi0xb,
                                                 TT * BB, H3, EE, 0, 1);
  // recurrent weights -> bf16 (wqb into dead xs region)
  k_conv<<<1024, 256, 0, stream>>>(Wq, wqb, 256, HH);
  k_conv<<<3072, 256, 0, stream>>>(Wih0, wi0b, 256, HH + EE);  // ctx cols only
  k_conv<<<3072, 256, 0, stream>>>(Whh0, wh0b, 256, HH);
  k_conv<<<3072, 256, 0, stream>>>(Wih1, wi1b, 256, HH);
  k_conv<<<3072, 256, 0, stream>>>(Whh1, wh1b, 256, HH);

  // the whole 64-step recurrence in one launch
  k_persist<<<NB, 256, 0, stream>>>(keysb, encb, gi0xb, wqb,
                                    wi0b, wh0b, wi1b, wh1b,
                                    wv, vlen, hid + BB * HH,
                                    bhh0, bih1, bhh1,
                                    qpart, scores, ctx, h0A, h0B, outs, bar);

  // logits = outs @ W_out^T + b_out  (fp32, permuted [t*B+b] -> [b,t])
  k_gemm_tiled<<<dim3(250, 16), 256, 0, stream>>>(outs, HH, Wout, HH, bout,
                                                  out, TT * BB, VV, HH, 1, 0);
}

// Round 6
// 9608.787 us; speedup vs baseline: 3.1324x; 3.1324x over previous
//
#include <hip/hip_runtime.h>

// ---------------------------------------------------------------------------
// Seq2SeqAttentionDecoder — round 6 (= round-5 plan, compile fix)
//
// R4 counters: FETCH 1.73GB = full weights re-fetched EVERY step; cause = the
// grid barrier's __threadfence() (device fence => per-XCD L2 writeback+inval
// on gfx950). Fix: NO fences anywhere.
//  * cross-block state (qpart/scores/ctx/h0/outs) via relaxed AGENT-scope
//    atomic ld/st (sc-bypass, coherent at L3). Producer order = the vmcnt(0)
//    drain __syncthreads() already emits. Consumer reads bypass stale L2.
//  * grid barrier = 2-level tree of relaxed atomics (8 group cnts -> root ->
//    release word), monotonic epochs, no cache maintenance.
//  * weights (bf16) in plain cached loads -> persist in per-XCD L2
//    (2 slices x 1.7MB = 3.4MB < 4MB). keys/enc/gi0x read nontemporal so
//    streams don't evict weights.
//  * GRU k-access strided (k = q4*8 + j*32): conflict-free LDS b128 reads
//    (R4's blocked k0=q4*256 was 4-way bank-conflicted).
//  * compile fix vs R5: nontemporal load uses ext_vector u16x4 (ushort4 is a
//    HIP class type -> rejected by __builtin_nontemporal_load).
// ---------------------------------------------------------------------------

#define BB 32
#define TT 64
#define SS 128
#define HH 1024
#define EE 512
#define VV 32000
#define H3 3072
#define NEGV (-1000000.0f)
#define NB 512          // persistent grid blocks (2/CU exact residency)

typedef __attribute__((ext_vector_type(8))) unsigned short u16x8;
typedef __attribute__((ext_vector_type(4))) unsigned short u16x4;

__device__ __forceinline__ unsigned short f2bf(float f) {
  unsigned int u = __builtin_bit_cast(unsigned int, f);
  unsigned int r = (u + 0x7FFFu + ((u >> 16) & 1u)) >> 16;   // RNE
  return (unsigned short)r;
}
__device__ __forceinline__ float bfu(unsigned short u) {
  return __builtin_bit_cast(float, (unsigned int)u << 16);
}
__device__ __forceinline__ float sigm(float x) {
  return 1.f / (1.f + __expf(-x));
}
__device__ __forceinline__ float tanhfast(float x) {
  float ax = fabsf(x);
  float e = __expf(2.f * ax);
  float th = 1.f - 2.f / (e + 1.f);
  return copysignf(th, x);
}
__device__ __forceinline__ void fma8(float& acc, u16x8 w, float4 x0, float4 x1) {
  acc = fmaf(bfu(w[0]), x0.x, acc); acc = fmaf(bfu(w[1]), x0.y, acc);
  acc = fmaf(bfu(w[2]), x0.z, acc); acc = fmaf(bfu(w[3]), x0.w, acc);
  acc = fmaf(bfu(w[4]), x1.x, acc); acc = fmaf(bfu(w[5]), x1.y, acc);
  acc = fmaf(bfu(w[6]), x1.z, acc); acc = fmaf(bfu(w[7]), x1.w, acc);
}
// uncached (L2-bypass, L3-coherent) state access — no fences needed
__device__ __forceinline__ float ldu(const float* p) {
  return __hip_atomic_load((float*)p, __ATOMIC_RELAXED, __HIP_MEMORY_SCOPE_AGENT);
}
__device__ __forceinline__ void stu(float* p, float v) {
  __hip_atomic_store(p, v, __ATOMIC_RELAXED, __HIP_MEMORY_SCOPE_AGENT);
}

// ---------- init: h0A = hidden[0], zero barrier words ----------
__global__ __launch_bounds__(256) void k_init(const float* __restrict__ hid,
                                              float* __restrict__ h0A,
                                              unsigned* __restrict__ bar) {
  int i = blockIdx.x * 256 + threadIdx.x;
  if (i < BB * HH) h0A[i] = hid[i];
  else if (i < BB * HH + 320) bar[i - BB * HH] = 0u;
}

// ---------- gather xs[r=t*B+b][e] = emb[X[b][t]][e]  (fp32) ----------
__global__ __launch_bounds__(256) void k_gather(const int* __restrict__ X,
                                                const float* __restrict__ emb,
                                                float* __restrict__ xs) {
  int idx = blockIdx.x * 256 + threadIdx.x;
  int r = idx >> 7, c4 = (idx & 127) << 2;
  int td = r >> 5, b = r & 31;
  int tok = X[b * TT + td];
  *(float4*)(xs + (size_t)r * EE + c4) =
      *(const float4*)(emb + (size_t)tok * EE + c4);
}

// ---------- fp32 -> packed bf16 (grid = rows) ----------
__global__ __launch_bounds__(256) void k_conv(const float* __restrict__ src,
                                              unsigned short* __restrict__ dst,
                                              int cols4, int ld) {
  int r = blockIdx.x;
  for (int c = threadIdx.x; c < cols4; c += 256) {
    float4 v = *(const float4*)(src + (size_t)r * ld + (size_t)c * 4);
    ushort4 o;
    o.x = f2bf(v.x); o.y = f2bf(v.y); o.z = f2bf(v.z); o.w = f2bf(v.w);
    *(ushort4*)(dst + (size_t)r * cols4 * 4 + (size_t)c * 4) = o;
  }
}

// ---------- fp32 tiled GEMM (proven): C = A @ W^T (+bias), opt bf16 out ----
__global__ __launch_bounds__(256) void k_gemm_tiled(
    const float* __restrict__ A, int lda,
    const float* __restrict__ W, int ldw,
    const float* __restrict__ bias,
    float* __restrict__ C, int M, int N, int K, int permuteBT, int outBF16) {
  __shared__ float As[16][132];
  __shared__ float Ws[16][132];
  const int m0 = blockIdx.y * 128, n0 = blockIdx.x * 128;
  const int t = threadIdx.x;
  const int tm = t >> 4, tn = t & 15;
  float acc[8][8] = {};
  for (int k0 = 0; k0 < K; k0 += 16) {
#pragma unroll
    for (int qq = 0; qq < 2; ++qq) {
      int f = t * 2 + qq;
      int row = f >> 2, c4 = (f & 3) << 2;
      float4 va = *(const float4*)(A + (size_t)(m0 + row) * lda + k0 + c4);
      As[c4 + 0][row] = va.x; As[c4 + 1][row] = va.y;
      As[c4 + 2][row] = va.z; As[c4 + 3][row] = va.w;
      float4 vw = *(const float4*)(W + (size_t)(n0 + row) * ldw + k0 + c4);
      Ws[c4 + 0][row] = vw.x; Ws[c4 + 1][row] = vw.y;
      Ws[c4 + 2][row] = vw.z; Ws[c4 + 3][row] = vw.w;
    }
    __syncthreads();
#pragma unroll
    for (int k = 0; k < 16; ++k) {
      float a[8], w[8];
      *(float4*)&a[0] = *(const float4*)&As[k][tm * 8];
      *(float4*)&a[4] = *(const float4*)&As[k][tm * 8 + 4];
      *(float4*)&w[0] = *(const float4*)&Ws[k][tn * 8];
      *(float4*)&w[4] = *(const float4*)&Ws[k][tn * 8 + 4];
#pragma unroll
      for (int i = 0; i < 8; ++i)
#pragma unroll
        for (int j = 0; j < 8; ++j) acc[i][j] = fmaf(a[i], w[j], acc[i][j]);
    }
    __syncthreads();
  }
#pragma unroll
  for (int i = 0; i < 8; ++i) {
    int m = m0 + tm * 8 + i;
    size_t rowoff = permuteBT ? ((size_t)((m & 31) * TT + (m >> 5))) * N
                              : (size_t)m * N;
#pragma unroll
    for (int jj = 0; jj < 2; ++jj) {
      int n = n0 + tn * 8 + jj * 4;
      float4 v;
      v.x = acc[i][jj * 4 + 0]; v.y = acc[i][jj * 4 + 1];
      v.z = acc[i][jj * 4 + 2]; v.w = acc[i][jj * 4 + 3];
      if (bias) { v.x += bias[n]; v.y += bias[n + 1];
                  v.z += bias[n + 2]; v.w += bias[n + 3]; }
      if (outBF16) {
        ushort4 o;
        o.x = f2bf(v.x); o.y = f2bf(v.y); o.z = f2bf(v.z); o.w = f2bf(v.w);
        *(ushort4*)((unsigned short*)C + rowoff + n) = o;
      } else {
        *(float4*)(C + rowoff + n) = v;
      }
    }
  }
}

// ---------- gates + GRU, one layer. block=(b, sl); strided-k 4-thread split --
// xg/hg: global fp32 state rows (pre-offset by b*HH), read uncached.
// wi/wh: bf16 [3*1024][1024] gate-major. gixrow: bf16 x-gates (pre-offset) or
// null. hdst pre-offset by b*HH. stash: LDS row for fused q-projection.
__device__ __forceinline__ void gru_phase(
    int sl, int t, float* shmx, float* shmy,
    const float* __restrict__ xg, const float* __restrict__ hg,
    const unsigned short* __restrict__ wi, const unsigned short* __restrict__ wh,
    const unsigned short* __restrict__ gixrow, const float* __restrict__ bih,
    const float* __restrict__ bhh, float* __restrict__ hdst, float* stash) {
  {
    const int i4 = t * 4;
    float4 xv, hv;
    xv.x = ldu(xg + i4);     xv.y = ldu(xg + i4 + 1);
    xv.z = ldu(xg + i4 + 2); xv.w = ldu(xg + i4 + 3);
    hv.x = ldu(hg + i4);     hv.y = ldu(hg + i4 + 1);
    hv.z = ldu(hg + i4 + 2); hv.w = ldu(hg + i4 + 3);
    *(float4*)(shmx + i4) = xv;
    *(float4*)(shmy + i4) = hv;
  }
  __syncthreads();
  const int nl = t >> 2, q4 = t & 3;
  const int n = sl * 64 + nl;
  const unsigned short* wr = wi + (size_t)n * HH + q4 * 8;
  const unsigned short* hr = wh + (size_t)n * HH + q4 * 8;
  float air = 0, aiz = 0, ain = 0, ahr = 0, ahz = 0, ahn = 0;
#pragma unroll 2
  for (int j = 0; j < 32; ++j) {
    const int k = q4 * 8 + j * 32;
    float4 x0 = *(const float4*)(shmx + k);
    float4 x1 = *(const float4*)(shmx + k + 4);
    float4 y0 = *(const float4*)(shmy + k);
    float4 y1 = *(const float4*)(shmy + k + 4);
    const unsigned short* wj = wr + j * 32;
    const unsigned short* hj = hr + j * 32;
    fma8(air, *(const u16x8*)(wj),           x0, x1);
    fma8(aiz, *(const u16x8*)(wj + 1048576), x0, x1);
    fma8(ain, *(const u16x8*)(wj + 2097152), x0, x1);
    fma8(ahr, *(const u16x8*)(hj),           y0, y1);
    fma8(ahz, *(const u16x8*)(hj + 1048576), y0, y1);
    fma8(ahn, *(const u16x8*)(hj + 2097152), y0, y1);
  }
  air += __shfl_xor(air, 1); air += __shfl_xor(air, 2);
  aiz += __shfl_xor(aiz, 1); aiz += __shfl_xor(aiz, 2);
  ain += __shfl_xor(ain, 1); ain += __shfl_xor(ain, 2);
  ahr += __shfl_xor(ahr, 1); ahr += __shfl_xor(ahr, 2);
  ahz += __shfl_xor(ahz, 1); ahz += __shfl_xor(ahz, 2);
  ahn += __shfl_xor(ahn, 1); ahn += __shfl_xor(ahn, 2);
  if (q4 == 0) {
    float gr = air, gz = aiz, gn = ain;
    if (gixrow) {
      gr += bfu(__builtin_nontemporal_load(gixrow + n));
      gz += bfu(__builtin_nontemporal_load(gixrow + HH + n));
      gn += bfu(__builtin_nontemporal_load(gixrow + 2 * HH + n));
    }
    if (bih) { gr += bih[n]; gz += bih[HH + n]; gn += bih[2 * HH + n]; }
    float h_r = ahr + bhh[n], h_z = ahz + bhh[HH + n], h_n = ahn + bhh[2 * HH + n];
    float r = sigm(gr + h_r);
    float z = sigm(gz + h_z);
    float nn = tanhfast(gn + r * h_n);
    float hv = (1.f - z) * nn + z * shmy[n];
    stu(hdst + n, hv);
    if (stash) stash[nl] = hv;
  }
}

// ---------- qpart[sl][b][nq..] = stash(64 k) @ Wq slice ----------
__device__ __forceinline__ void qpart_phase(
    int b, int sl, int t, const float* stash,
    const unsigned short* __restrict__ wqb, float* __restrict__ qpart) {
  const int nq = t * 4;
  const unsigned short* w0 = wqb + (size_t)nq * HH + sl * 64;
  float a0 = 0, a1 = 0, a2 = 0, a3 = 0;
#pragma unroll
  for (int k8 = 0; k8 < 8; ++k8) {
    float4 x0 = *(const float4*)(stash + k8 * 8);
    float4 x1 = *(const float4*)(stash + k8 * 8 + 4);
    fma8(a0, *(const u16x8*)(w0 + k8 * 8),          x0, x1);
    fma8(a1, *(const u16x8*)(w0 + HH + k8 * 8),     x0, x1);
    fma8(a2, *(const u16x8*)(w0 + 2 * HH + k8 * 8), x0, x1);
    fma8(a3, *(const u16x8*)(w0 + 3 * HH + k8 * 8), x0, x1);
  }
  float* qp = qpart + ((size_t)sl * BB + b) * HH + nq;
  stu(qp, a0); stu(qp + 1, a1); stu(qp + 2, a2); stu(qp + 3, a3);
}

// ---------- the persistent recurrence kernel (fence-free) ----------
__global__ __launch_bounds__(256, 2) void k_persist(
    const unsigned short* __restrict__ keysb,
    const unsigned short* __restrict__ gi0xb,
    const unsigned short* __restrict__ wqb,
    const unsigned short* __restrict__ wi0, const unsigned short* __restrict__ wh0,
    const unsigned short* __restrict__ wi1, const unsigned short* __restrict__ wh1,
    const float* __restrict__ enc, const float* __restrict__ wv,
    const int* __restrict__ vlen, const float* __restrict__ hid1,
    const float* __restrict__ bhh0, const float* __restrict__ bih1,
    const float* __restrict__ bhh1,
    float* __restrict__ qpart, float* __restrict__ scores,
    float* __restrict__ ctx,
    float* __restrict__ h0A, float* __restrict__ h0B, float* __restrict__ outs,
    unsigned* __restrict__ bar) {
  __shared__ float shm[2496];   // [0,1024) x | [1024,2048) y | [2048,2112) stash
  float* shmx  = shm;           // | [2112,2496) aux
  float* shmy  = shm + 1024;
  float* stash = shm + 2048;
  float* aux   = shm + 2112;
  const int bid = blockIdx.x, t = threadIdx.x;
  const int b = bid >> 4, sl = bid & 15;
  unsigned* root = bar + 256;
  unsigned* rel  = bar + 288;
  unsigned ep = 0;

  // fence-free tree barrier: relaxed agent atomics only (no L2 flush/inval).
  // __syncthreads() drains vmcnt -> this block's sc-bypass stores are at the
  // coherence point before the arrive-add.
#define GBAR() do { ++ep; __syncthreads();                                     \
    if (t == 0) {                                                              \
      unsigned prev = __hip_atomic_fetch_add(bar + (bid & 7) * 32, 1u,         \
                        __ATOMIC_RELAXED, __HIP_MEMORY_SCOPE_AGENT);           \
      if (prev == ep * 64u - 1u) {                                             \
        unsigned pr = __hip_atomic_fetch_add(root, 1u,                         \
                        __ATOMIC_RELAXED, __HIP_MEMORY_SCOPE_AGENT);           \
        if (pr == ep * 8u - 1u)                                                \
          __hip_atomic_store(rel, ep, __ATOMIC_RELAXED,                        \
                             __HIP_MEMORY_SCOPE_AGENT);                        \
      }                                                                        \
      while (__hip_atomic_load(rel, __ATOMIC_RELAXED,                          \
                               __HIP_MEMORY_SCOPE_AGENT) < ep)                 \
        __builtin_amdgcn_s_sleep(1);                                           \
      asm volatile("" ::: "memory");                                           \
    }                                                                          \
    __syncthreads(); } while (0)

  // ---- P0 (once): qpart from initial h1 = hid1 ----
  if (t < 16)
    *(float4*)(stash + t * 4) = *(const float4*)(hid1 + b * HH + sl * 64 + t * 4);
  __syncthreads();
  qpart_phase(b, sl, t, stash, wqb, qpart);
  GBAR();

  for (int td = 0; td < TT; ++td) {
    const float* h1old = td ? outs + (size_t)(td - 1) * BB * HH : hid1;
    const float* h0old = (td & 1) ? h0B : h0A;
    float*       h0new = (td & 1) ? h0A : h0B;

    // ---- P2: scores[b][s] = sum_h tanh(q+keys)*wv (8 s per block) ----
    {
      const int i4 = t * 4;
      float4 a = {0, 0, 0, 0};
#pragma unroll
      for (int p = 0; p < 16; ++p) {
        const float* qp = qpart + ((size_t)p * BB + b) * HH + i4;
        a.x += ldu(qp);     a.y += ldu(qp + 1);
        a.z += ldu(qp + 2); a.w += ldu(qp + 3);
      }
      *(float4*)(shmx + i4) = a;
      __syncthreads();
      const int s_loc = t >> 5, g = t & 31;
      const int s = sl * 8 + s_loc;
      const unsigned short* kr = keysb + (size_t)(b * SS + s) * HH;
      float acc = 0;
#pragma unroll
      for (int kk = 0; kk < 8; ++kk) {
        const int h = (g + kk * 32) * 4;
        float4 qv = *(const float4*)(shmx + h);
        u16x4 kv = __builtin_nontemporal_load((const u16x4*)(kr + h));
        float4 wvv = *(const float4*)(wv + h);
        acc = fmaf(tanhfast(qv.x + bfu(kv[0])), wvv.x, acc);
        acc = fmaf(tanhfast(qv.y + bfu(kv[1])), wvv.y, acc);
        acc = fmaf(tanhfast(qv.z + bfu(kv[2])), wvv.z, acc);
        acc = fmaf(tanhfast(qv.w + bfu(kv[3])), wvv.w, acc);
      }
      acc += __shfl_xor(acc, 1); acc += __shfl_xor(acc, 2);
      acc += __shfl_xor(acc, 4); acc += __shfl_xor(acc, 8);
      acc += __shfl_xor(acc, 16);
      if (g == 0) stu(scores + b * SS + s, (s < vlen[b]) ? acc : NEGV);
    }
    GBAR();

    // ---- P3: softmax + ctx slice (64 c-columns) ----
    {
      if (t < SS) aux[t] = ldu(scores + b * SS + t);
      __syncthreads();
      float mx = aux[0];
#pragma unroll 8
      for (int s = 1; s < SS; ++s) mx = fmaxf(mx, aux[s]);
      float p = (t < SS) ? __expf(aux[t] - mx) : 0.f;
      __syncthreads();
      if (t < SS) aux[t] = p;
      __syncthreads();
      float sum = 0;
#pragma unroll 8
      for (int s = 0; s < SS; ++s) sum += aux[s];
      const float inv = 1.f / sum;
      const int cl = t & 63, sg = t >> 6;     // 4 s-groups x 32 s
      const float* ep2 = enc + (size_t)b * SS * HH + sl * 64 + cl;
      float a = 0;
#pragma unroll 4
      for (int s = sg * 32; s < sg * 32 + 32; ++s)
        a = fmaf(aux[s], __builtin_nontemporal_load(ep2 + (size_t)s * HH), a);
      aux[SS + sg * 64 + cl] = a;
      __syncthreads();
      if (t < 64) {
        float v = (aux[SS + t] + aux[SS + 64 + t] +
                   aux[SS + 128 + t] + aux[SS + 192 + t]) * inv;
        stu(ctx + b * HH + sl * 64 + t, v);
      }
    }
    GBAR();

    // ---- P4: layer-0 gates + GRU -> h0new ----
    gru_phase(sl, t, shmx, shmy, ctx + b * HH, h0old + b * HH, wi0, wh0,
              gi0xb + ((size_t)td * BB + b) * H3, nullptr, bhh0,
              h0new + b * HH, nullptr);
    GBAR();

    // ---- P5: layer-1 gates + GRU -> outs[td]; fused q-proj for next step ----
    gru_phase(sl, t, shmx, shmy, h0new + b * HH, h1old + b * HH, wi1, wh1,
              nullptr, bih1, bhh1, outs + (size_t)td * BB * HH + b * HH, stash);
    if (td < TT - 1) {
      __syncthreads();
      qpart_phase(b, sl, t, stash, wqb, qpart);
    }
    GBAR();
  }
#undef GBAR
}

// ---------------------------------------------------------------------------
extern "C" void kernel_launch(void* const* d_in, const int* in_sizes, int n_in,
                              void* d_out, int out_size, void* d_ws,
                              size_t ws_size, hipStream_t stream) {
  const int*   X    = (const int*)  d_in[0];
  const float* enc  = (const float*)d_in[1];
  const float* hid  = (const float*)d_in[2];
  const int*   vlen = (const int*)  d_in[3];
  const float* emb  = (const float*)d_in[4];
  const float* Wq   = (const float*)d_in[5];
  const float* Wk   = (const float*)d_in[6];
  const float* wv   = (const float*)d_in[7];
  const float* Wih0 = (const float*)d_in[8];
  const float* Whh0 = (const float*)d_in[9];
  const float* bih0 = (const float*)d_in[10];
  const float* bhh0 = (const float*)d_in[11];
  const float* Wih1 = (const float*)d_in[12];
  const float* Whh1 = (const float*)d_in[13];
  const float* bih1 = (const float*)d_in[14];
  const float* bhh1 = (const float*)d_in[15];
  const float* Wout = (const float*)d_in[16];
  const float* bout = (const float*)d_in[17];
  float* out = (float*)d_out;

  // ---- workspace (float offsets), total ~15.32M f = 61.3 MB ----
  float* ws = (float*)d_ws;
  unsigned short* wi0b  = (unsigned short*)ws;              // 4 gate mats, bf16
  unsigned short* wh0b  = wi0b + (size_t)3145728;           // (6,291,456 f all)
  unsigned short* wi1b  = wh0b + (size_t)3145728;
  unsigned short* wh1b  = wi1b + (size_t)3145728;
  float*          outs  = ws + 6291456;                     // 2,097,152
  float*          xs    = ws + 8388608;                     // 1,048,576 (dead after gi0x)
  unsigned short* wqb   = (unsigned short*)xs;              // alias, post-gi0x
  unsigned short* gi0xb = (unsigned short*)(ws + 9437184);  // 3,145,728 f worth
  unsigned short* keysb = (unsigned short*)(ws + 12582912); // 2,097,152 f worth
  float*          qpart = ws + 14680064;                    //   524,288
  float*          h0A   = ws + 15204352;                    //    32,768
  float*          h0B   = ws + 15237120;                    //    32,768
  float*          ctx   = ws + 15269888;                    //    32,768
  float*          scores= ws + 15302656;                    //     4,096
  unsigned*       bar   = (unsigned*)(ws + 15306752);       //       320 u

  k_init<<<130, 256, 0, stream>>>(hid, h0A, bar);
  k_gather<<<1024, 256, 0, stream>>>(X, emb, xs);
  // keysb = bf16(enc @ Wk^T)
  k_gemm_tiled<<<dim3(8, 32), 256, 0, stream>>>(enc, HH, Wk, HH, nullptr,
                                                (float*)keysb, BB * SS, HH, HH,
                                                0, 1);
  // gi0xb = bf16(xs @ W_ih0[:,H:]^T + b_ih0)   (consumes xs)
  k_gemm_tiled<<<dim3(24, 16), 256, 0, stream>>>(xs, EE, Wih0 + HH, HH + EE,
                                                 bih0, (float*)gi0xb,
                                                 TT * BB, H3, EE, 0, 1);
  // recurrent weights -> bf16 (wqb into dead xs region, AFTER gi0x GEMM)
  k_conv<<<1024, 256, 0, stream>>>(Wq, wqb, 256, HH);
  k_conv<<<3072, 256, 0, stream>>>(Wih0, wi0b, 256, HH + EE);  // ctx cols only
  k_conv<<<3072, 256, 0, stream>>>(Whh0, wh0b, 256, HH);
  k_conv<<<3072, 256, 0, stream>>>(Wih1, wi1b, 256, HH);
  k_conv<<<3072, 256, 0, stream>>>(Whh1, wh1b, 256, HH);

  // the whole 64-step recurrence, one launch, fence-free sync
  k_persist<<<NB, 256, 0, stream>>>(keysb, gi0xb, wqb,
                                    wi0b, wh0b, wi1b, wh1b,
                                    enc, wv, vlen, hid + BB * HH,
                                    bhh0, bih1, bhh1,
                                    qpart, scores, ctx, h0A, h0B, outs, bar);

  // logits = outs @ W_out^T + b_out  (fp32, permuted [t*B+b] -> [b,t])
  k_gemm_tiled<<<dim3(250, 16), 256, 0, stream>>>(outs, HH, Wout, HH, bout,
                                                  out, TT * BB, VV, HH, 1, 0);
}

// Round 7
// 8598.627 us; speedup vs baseline: 3.5004x; 1.1175x over previous
//
#include <hip/hip_runtime.h>

// ---------------------------------------------------------------------------
// Seq2SeqAttentionDecoder — round 7: fence-free persistent recurrence v2
//
// R6 counters: k_persist 7.9ms, VALUBusy 25%, FETCH 3.38GB = 52.7MB/step =
// full weights+streams refetched (nt hints forced keys/enc to HBM every step
// and streams evicted weights; per-XCD set 6.3MB > 4MB L2).
// R7 fixes (minimal diff from passing R6):
//  * NO nt hints anywhere (R3 evidence: plain loads keep weights L2-resident)
//  * enc -> bf16 (encb) for the ctx accumulation (halves biggest stream)
//  * vlen-skip: s >= vlen[b] rows of keys/enc never read (math identical:
//    masked scores are NEG -> softmax weight exactly 0). E[vlen]~64/128.
//  * per-XCD set now ~4.3MB: weights 3.07 + wq .25 + keys ~.5 + enc ~.5
// Everything else (barrier, phases, gru math) identical to R6.
// ---------------------------------------------------------------------------

#define BB 32
#define TT 64
#define SS 128
#define HH 1024
#define EE 512
#define VV 32000
#define H3 3072
#define NEGV (-1000000.0f)
#define NB 512          // persistent grid blocks (2/CU exact residency)

typedef __attribute__((ext_vector_type(8))) unsigned short u16x8;
typedef __attribute__((ext_vector_type(4))) unsigned short u16x4;

__device__ __forceinline__ unsigned short f2bf(float f) {
  unsigned int u = __builtin_bit_cast(unsigned int, f);
  unsigned int r = (u + 0x7FFFu + ((u >> 16) & 1u)) >> 16;   // RNE
  return (unsigned short)r;
}
__device__ __forceinline__ float bfu(unsigned short u) {
  return __builtin_bit_cast(float, (unsigned int)u << 16);
}
__device__ __forceinline__ float sigm(float x) {
  return 1.f / (1.f + __expf(-x));
}
__device__ __forceinline__ float tanhfast(float x) {
  float ax = fabsf(x);
  float e = __expf(2.f * ax);
  float th = 1.f - 2.f / (e + 1.f);
  return copysignf(th, x);
}
__device__ __forceinline__ void fma8(float& acc, u16x8 w, float4 x0, float4 x1) {
  acc = fmaf(bfu(w[0]), x0.x, acc); acc = fmaf(bfu(w[1]), x0.y, acc);
  acc = fmaf(bfu(w[2]), x0.z, acc); acc = fmaf(bfu(w[3]), x0.w, acc);
  acc = fmaf(bfu(w[4]), x1.x, acc); acc = fmaf(bfu(w[5]), x1.y, acc);
  acc = fmaf(bfu(w[6]), x1.z, acc); acc = fmaf(bfu(w[7]), x1.w, acc);
}
// L3-coherent state access (agent-scope relaxed atomics) — no fences needed
__device__ __forceinline__ float ldu(const float* p) {
  return __hip_atomic_load((float*)p, __ATOMIC_RELAXED, __HIP_MEMORY_SCOPE_AGENT);
}
__device__ __forceinline__ void stu(float* p, float v) {
  __hip_atomic_store(p, v, __ATOMIC_RELAXED, __HIP_MEMORY_SCOPE_AGENT);
}

// ---------- init: h0A = hidden[0], zero barrier words ----------
__global__ __launch_bounds__(256) void k_init(const float* __restrict__ hid,
                                              float* __restrict__ h0A,
                                              unsigned* __restrict__ bar) {
  int i = blockIdx.x * 256 + threadIdx.x;
  if (i < BB * HH) h0A[i] = hid[i];
  else if (i < BB * HH + 320) bar[i - BB * HH] = 0u;
}

// ---------- gather xs[r=t*B+b][e] = emb[X[b][t]][e]  (fp32) ----------
__global__ __launch_bounds__(256) void k_gather(const int* __restrict__ X,
                                                const float* __restrict__ emb,
                                                float* __restrict__ xs) {
  int idx = blockIdx.x * 256 + threadIdx.x;
  int r = idx >> 7, c4 = (idx & 127) << 2;
  int td = r >> 5, b = r & 31;
  int tok = X[b * TT + td];
  *(float4*)(xs + (size_t)r * EE + c4) =
      *(const float4*)(emb + (size_t)tok * EE + c4);
}

// ---------- fp32 -> packed bf16 (grid = rows) ----------
__global__ __launch_bounds__(256) void k_conv(const float* __restrict__ src,
                                              unsigned short* __restrict__ dst,
                                              int cols4, int ld) {
  int r = blockIdx.x;
  for (int c = threadIdx.x; c < cols4; c += 256) {
    float4 v = *(const float4*)(src + (size_t)r * ld + (size_t)c * 4);
    ushort4 o;
    o.x = f2bf(v.x); o.y = f2bf(v.y); o.z = f2bf(v.z); o.w = f2bf(v.w);
    *(ushort4*)(dst + (size_t)r * cols4 * 4 + (size_t)c * 4) = o;
  }
}

// ---------- fp32 tiled GEMM (proven): C = A @ W^T (+bias), opt bf16 out ----
__global__ __launch_bounds__(256) void k_gemm_tiled(
    const float* __restrict__ A, int lda,
    const float* __restrict__ W, int ldw,
    const float* __restrict__ bias,
    float* __restrict__ C, int M, int N, int K, int permuteBT, int outBF16) {
  __shared__ float As[16][132];
  __shared__ float Ws[16][132];
  const int m0 = blockIdx.y * 128, n0 = blockIdx.x * 128;
  const int t = threadIdx.x;
  const int tm = t >> 4, tn = t & 15;
  float acc[8][8] = {};
  for (int k0 = 0; k0 < K; k0 += 16) {
#pragma unroll
    for (int qq = 0; qq < 2; ++qq) {
      int f = t * 2 + qq;
      int row = f >> 2, c4 = (f & 3) << 2;
      float4 va = *(const float4*)(A + (size_t)(m0 + row) * lda + k0 + c4);
      As[c4 + 0][row] = va.x; As[c4 + 1][row] = va.y;
      As[c4 + 2][row] = va.z; As[c4 + 3][row] = va.w;
      float4 vw = *(const float4*)(W + (size_t)(n0 + row) * ldw + k0 + c4);
      Ws[c4 + 0][row] = vw.x; Ws[c4 + 1][row] = vw.y;
      Ws[c4 + 2][row] = vw.z; Ws[c4 + 3][row] = vw.w;
    }
    __syncthreads();
#pragma unroll
    for (int k = 0; k < 16; ++k) {
      float a[8], w[8];
      *(float4*)&a[0] = *(const float4*)&As[k][tm * 8];
      *(float4*)&a[4] = *(const float4*)&As[k][tm * 8 + 4];
      *(float4*)&w[0] = *(const float4*)&Ws[k][tn * 8];
      *(float4*)&w[4] = *(const float4*)&Ws[k][tn * 8 + 4];
#pragma unroll
      for (int i = 0; i < 8; ++i)
#pragma unroll
        for (int j = 0; j < 8; ++j) acc[i][j] = fmaf(a[i], w[j], acc[i][j]);
    }
    __syncthreads();
  }
#pragma unroll
  for (int i = 0; i < 8; ++i) {
    int m = m0 + tm * 8 + i;
    size_t rowoff = permuteBT ? ((size_t)((m & 31) * TT + (m >> 5))) * N
                              : (size_t)m * N;
#pragma unroll
    for (int jj = 0; jj < 2; ++jj) {
      int n = n0 + tn * 8 + jj * 4;
      float4 v;
      v.x = acc[i][jj * 4 + 0]; v.y = acc[i][jj * 4 + 1];
      v.z = acc[i][jj * 4 + 2]; v.w = acc[i][jj * 4 + 3];
      if (bias) { v.x += bias[n]; v.y += bias[n + 1];
                  v.z += bias[n + 2]; v.w += bias[n + 3]; }
      if (outBF16) {
        ushort4 o;
        o.x = f2bf(v.x); o.y = f2bf(v.y); o.z = f2bf(v.z); o.w = f2bf(v.w);
        *(ushort4*)((unsigned short*)C + rowoff + n) = o;
      } else {
        *(float4*)(C + rowoff + n) = v;
      }
    }
  }
}

// ---------- gates + GRU, one layer. block=(b, sl); strided-k 4-thread split --
__device__ __forceinline__ void gru_phase(
    int sl, int t, float* shmx, float* shmy,
    const float* __restrict__ xg, const float* __restrict__ hg,
    const unsigned short* __restrict__ wi, const unsigned short* __restrict__ wh,
    const unsigned short* __restrict__ gixrow, const float* __restrict__ bih,
    const float* __restrict__ bhh, float* __restrict__ hdst, float* stash) {
  {
    const int i4 = t * 4;
    float4 xv, hv;
    xv.x = ldu(xg + i4);     xv.y = ldu(xg + i4 + 1);
    xv.z = ldu(xg + i4 + 2); xv.w = ldu(xg + i4 + 3);
    hv.x = ldu(hg + i4);     hv.y = ldu(hg + i4 + 1);
    hv.z = ldu(hg + i4 + 2); hv.w = ldu(hg + i4 + 3);
    *(float4*)(shmx + i4) = xv;
    *(float4*)(shmy + i4) = hv;
  }
  __syncthreads();
  const int nl = t >> 2, q4 = t & 3;
  const int n = sl * 64 + nl;
  const unsigned short* wr = wi + (size_t)n * HH + q4 * 8;
  const unsigned short* hr = wh + (size_t)n * HH + q4 * 8;
  float air = 0, aiz = 0, ain = 0, ahr = 0, ahz = 0, ahn = 0;
#pragma unroll 2
  for (int j = 0; j < 32; ++j) {
    const int k = q4 * 8 + j * 32;
    float4 x0 = *(const float4*)(shmx + k);
    float4 x1 = *(const float4*)(shmx + k + 4);
    float4 y0 = *(const float4*)(shmy + k);
    float4 y1 = *(const float4*)(shmy + k + 4);
    const unsigned short* wj = wr + j * 32;
    const unsigned short* hj = hr + j * 32;
    fma8(air, *(const u16x8*)(wj),           x0, x1);
    fma8(aiz, *(const u16x8*)(wj + 1048576), x0, x1);
    fma8(ain, *(const u16x8*)(wj + 2097152), x0, x1);
    fma8(ahr, *(const u16x8*)(hj),           y0, y1);
    fma8(ahz, *(const u16x8*)(hj + 1048576), y0, y1);
    fma8(ahn, *(const u16x8*)(hj + 2097152), y0, y1);
  }
  air += __shfl_xor(air, 1); air += __shfl_xor(air, 2);
  aiz += __shfl_xor(aiz, 1); aiz += __shfl_xor(aiz, 2);
  ain += __shfl_xor(ain, 1); ain += __shfl_xor(ain, 2);
  ahr += __shfl_xor(ahr, 1); ahr += __shfl_xor(ahr, 2);
  ahz += __shfl_xor(ahz, 1); ahz += __shfl_xor(ahz, 2);
  ahn += __shfl_xor(ahn, 1); ahn += __shfl_xor(ahn, 2);
  if (q4 == 0) {
    float gr = air, gz = aiz, gn = ain;
    if (gixrow) {
      gr += bfu(gixrow[n]);
      gz += bfu(gixrow[HH + n]);
      gn += bfu(gixrow[2 * HH + n]);
    }
    if (bih) { gr += bih[n]; gz += bih[HH + n]; gn += bih[2 * HH + n]; }
    float h_r = ahr + bhh[n], h_z = ahz + bhh[HH + n], h_n = ahn + bhh[2 * HH + n];
    float r = sigm(gr + h_r);
    float z = sigm(gz + h_z);
    float nn = tanhfast(gn + r * h_n);
    float hv = (1.f - z) * nn + z * shmy[n];
    stu(hdst + n, hv);
    if (stash) stash[nl] = hv;
  }
}

// ---------- qpart[sl][b][nq..] = stash(64 k) @ Wq slice ----------
__device__ __forceinline__ void qpart_phase(
    int b, int sl, int t, const float* stash,
    const unsigned short* __restrict__ wqb, float* __restrict__ qpart) {
  const int nq = t * 4;
  const unsigned short* w0 = wqb + (size_t)nq * HH + sl * 64;
  float a0 = 0, a1 = 0, a2 = 0, a3 = 0;
#pragma unroll
  for (int k8 = 0; k8 < 8; ++k8) {
    float4 x0 = *(const float4*)(stash + k8 * 8);
    float4 x1 = *(const float4*)(stash + k8 * 8 + 4);
    fma8(a0, *(const u16x8*)(w0 + k8 * 8),          x0, x1);
    fma8(a1, *(const u16x8*)(w0 + HH + k8 * 8),     x0, x1);
    fma8(a2, *(const u16x8*)(w0 + 2 * HH + k8 * 8), x0, x1);
    fma8(a3, *(const u16x8*)(w0 + 3 * HH + k8 * 8), x0, x1);
  }
  float* qp = qpart + ((size_t)sl * BB + b) * HH + nq;
  stu(qp, a0); stu(qp + 1, a1); stu(qp + 2, a2); stu(qp + 3, a3);
}

// ---------- the persistent recurrence kernel (fence-free) ----------
__global__ __launch_bounds__(256, 2) void k_persist(
    const unsigned short* __restrict__ keysb,
    const unsigned short* __restrict__ encb,
    const unsigned short* __restrict__ gi0xb,
    const unsigned short* __restrict__ wqb,
    const unsigned short* __restrict__ wi0, const unsigned short* __restrict__ wh0,
    const unsigned short* __restrict__ wi1, const unsigned short* __restrict__ wh1,
    const float* __restrict__ wv, const int* __restrict__ vlen,
    const float* __restrict__ hid1,
    const float* __restrict__ bhh0, const float* __restrict__ bih1,
    const float* __restrict__ bhh1,
    float* __restrict__ qpart, float* __restrict__ scores,
    float* __restrict__ ctx,
    float* __restrict__ h0A, float* __restrict__ h0B, float* __restrict__ outs,
    unsigned* __restrict__ bar) {
  __shared__ float shm[2752];   // [0,1024) x | [1024,2048) y | [2048,2112)
  float* shmx  = shm;           //   stash | [2112,2752) aux (128 + 512)
  float* shmy  = shm + 1024;
  float* stash = shm + 2048;
  float* aux   = shm + 2112;
  const int bid = blockIdx.x, t = threadIdx.x;
  const int b = bid >> 4, sl = bid & 15;
  const int vb = vlen[b];       // 1..127; rows s >= vb contribute exactly 0
  unsigned* root = bar + 256;
  unsigned* rel  = bar + 288;
  unsigned ep = 0;

#define GBAR() do { ++ep; __syncthreads();                                     \
    if (t == 0) {                                                              \
      unsigned prev = __hip_atomic_fetch_add(bar + (bid & 7) * 32, 1u,         \
                        __ATOMIC_RELAXED, __HIP_MEMORY_SCOPE_AGENT);           \
      if (prev == ep * 64u - 1u) {                                             \
        unsigned pr = __hip_atomic_fetch_add(root, 1u,                         \
                        __ATOMIC_RELAXED, __HIP_MEMORY_SCOPE_AGENT);           \
        if (pr == ep * 8u - 1u)                                                \
          __hip_atomic_store(rel, ep, __ATOMIC_RELAXED,                        \
                             __HIP_MEMORY_SCOPE_AGENT);                        \
      }                                                                        \
      while (__hip_atomic_load(rel, __ATOMIC_RELAXED,                          \
                               __HIP_MEMORY_SCOPE_AGENT) < ep)                 \
        __builtin_amdgcn_s_sleep(1);                                           \
      asm volatile("" ::: "memory");                                           \
    }                                                                          \
    __syncthreads(); } while (0)

  // ---- P0 (once): qpart from initial h1 = hid1 ----
  if (t < 16)
    *(float4*)(stash + t * 4) = *(const float4*)(hid1 + b * HH + sl * 64 + t * 4);
  __syncthreads();
  qpart_phase(b, sl, t, stash, wqb, qpart);
  GBAR();

  for (int td = 0; td < TT; ++td) {
    const float* h1old = td ? outs + (size_t)(td - 1) * BB * HH : hid1;
    const float* h0old = (td & 1) ? h0B : h0A;
    float*       h0new = (td & 1) ? h0A : h0B;

    // ---- P2: scores[b][s] = sum_h tanh(q+keys)*wv (8 s per block) ----
    {
      const int i4 = t * 4;
      float4 a = {0, 0, 0, 0};
#pragma unroll
      for (int p = 0; p < 16; ++p) {
        const float* qp = qpart + ((size_t)p * BB + b) * HH + i4;
        a.x += ldu(qp);     a.y += ldu(qp + 1);
        a.z += ldu(qp + 2); a.w += ldu(qp + 3);
      }
      *(float4*)(shmx + i4) = a;
      __syncthreads();
      const int s_loc = t >> 5, g = t & 31;
      const int s = sl * 8 + s_loc;
      float acc = 0;
      if (s < vb) {                        // uniform per 32-lane half
        const unsigned short* kr = keysb + (size_t)(b * SS + s) * HH;
#pragma unroll
        for (int kk = 0; kk < 8; ++kk) {
          const int h = (g + kk * 32) * 4;
          float4 qv = *(const float4*)(shmx + h);
          u16x4 kv = *(const u16x4*)(kr + h);
          float4 wvv = *(const float4*)(wv + h);
          acc = fmaf(tanhfast(qv.x + bfu(kv[0])), wvv.x, acc);
          acc = fmaf(tanhfast(qv.y + bfu(kv[1])), wvv.y, acc);
          acc = fmaf(tanhfast(qv.z + bfu(kv[2])), wvv.z, acc);
          acc = fmaf(tanhfast(qv.w + bfu(kv[3])), wvv.w, acc);
        }
        acc += __shfl_xor(acc, 1); acc += __shfl_xor(acc, 2);
        acc += __shfl_xor(acc, 4); acc += __shfl_xor(acc, 8);
        acc += __shfl_xor(acc, 16);
      }
      if (g == 0) stu(scores + b * SS + s, (s < vb) ? acc : NEGV);
    }
    GBAR();

    // ---- P3: softmax + ctx slice (64 c-columns, bf16 enc, vlen-clamped) ----
    {
      if (t < SS) aux[t] = ldu(scores + b * SS + t);
      __syncthreads();
      float mx = aux[0];
      for (int s = 1; s < vb; ++s) mx = fmaxf(mx, aux[s]);
      float p = (t < SS) ? __expf(aux[t] - mx) : 0.f;   // s>=vb -> exp(NEG)=0
      __syncthreads();
      if (t < SS) aux[t] = p;
      __syncthreads();
      float sum = 0;
      for (int s = 0; s < vb; ++s) sum += aux[s];
      const float inv = 1.f / sum;
      const int cp = t & 31, sg = t >> 5;   // 32 col-pairs x 8 s-groups(16 s)
      const unsigned short* eb = encb + (size_t)b * SS * HH + sl * 64 + cp * 2;
      float a0 = 0, a1 = 0;
      const int send = min((sg + 1) * 16, vb);
      for (int s = sg * 16; s < send; ++s) {
        unsigned e2 = *(const unsigned*)(eb + (size_t)s * HH);
        float pp = aux[s];
        a0 = fmaf(pp, bfu((unsigned short)(e2 & 0xffffu)), a0);
        a1 = fmaf(pp, bfu((unsigned short)(e2 >> 16)), a1);
      }
      aux[SS + sg * 64 + cp * 2]     = a0;
      aux[SS + sg * 64 + cp * 2 + 1] = a1;
      __syncthreads();
      if (t < 64) {
        float v = 0;
#pragma unroll
        for (int g2 = 0; g2 < 8; ++g2) v += aux[SS + g2 * 64 + t];
        stu(ctx + b * HH + sl * 64 + t, v * inv);
      }
    }
    GBAR();

    // ---- P4: layer-0 gates + GRU -> h0new ----
    gru_phase(sl, t, shmx, shmy, ctx + b * HH, h0old + b * HH, wi0, wh0,
              gi0xb + ((size_t)td * BB + b) * H3, nullptr, bhh0,
              h0new + b * HH, nullptr);
    GBAR();

    // ---- P5: layer-1 gates + GRU -> outs[td]; fused q-proj for next step ----
    gru_phase(sl, t, shmx, shmy, h0new + b * HH, h1old + b * HH, wi1, wh1,
              nullptr, bih1, bhh1, outs + (size_t)td * BB * HH + b * HH, stash);
    if (td < TT - 1) {
      __syncthreads();
      qpart_phase(b, sl, t, stash, wqb, qpart);
    }
    GBAR();
  }
#undef GBAR
}

// ---------------------------------------------------------------------------
extern "C" void kernel_launch(void* const* d_in, const int* in_sizes, int n_in,
                              void* d_out, int out_size, void* d_ws,
                              size_t ws_size, hipStream_t stream) {
  const int*   X    = (const int*)  d_in[0];
  const float* enc  = (const float*)d_in[1];
  const float* hid  = (const float*)d_in[2];
  const int*   vlen = (const int*)  d_in[3];
  const float* emb  = (const float*)d_in[4];
  const float* Wq   = (const float*)d_in[5];
  const float* Wk   = (const float*)d_in[6];
  const float* wv   = (const float*)d_in[7];
  const float* Wih0 = (const float*)d_in[8];
  const float* Whh0 = (const float*)d_in[9];
  const float* bih0 = (const float*)d_in[10];
  const float* bhh0 = (const float*)d_in[11];
  const float* Wih1 = (const float*)d_in[12];
  const float* Whh1 = (const float*)d_in[13];
  const float* bih1 = (const float*)d_in[14];
  const float* bhh1 = (const float*)d_in[15];
  const float* Wout = (const float*)d_in[16];
  const float* bout = (const float*)d_in[17];
  float* out = (float*)d_out;

  // ---- workspace (float offsets), total ~17.40M f = 69.6 MB ----
  float* ws = (float*)d_ws;
  unsigned short* wi0b  = (unsigned short*)ws;              // 4 gate mats, bf16
  unsigned short* wh0b  = wi0b + (size_t)3145728;
  unsigned short* wi1b  = wh0b + (size_t)3145728;
  unsigned short* wh1b  = wi1b + (size_t)3145728;
  float*          outs  = ws + 6291456;                     // 2,097,152
  float*          xs    = ws + 8388608;                     // 1,048,576 (dead after gi0x)
  unsigned short* wqb   = (unsigned short*)xs;              // alias, post-gi0x
  unsigned short* gi0xb = (unsigned short*)(ws + 9437184);  // 3,145,728 f worth
  unsigned short* keysb = (unsigned short*)(ws + 12582912); // 2,097,152 f worth
  unsigned short* encb  = (unsigned short*)(ws + 14680064); // 2,097,152 f worth
  float*          qpart = ws + 16777216;                    //   524,288
  float*          h0A   = ws + 17301504;                    //    32,768
  float*          h0B   = ws + 17334272;                    //    32,768
  float*          ctx   = ws + 17367040;                    //    32,768
  float*          scores= ws + 17399808;                    //     4,096
  unsigned*       bar   = (unsigned*)(ws + 17403904);       //       320 u

  k_init<<<130, 256, 0, stream>>>(hid, h0A, bar);
  k_gather<<<1024, 256, 0, stream>>>(X, emb, xs);
  // keysb = bf16(enc @ Wk^T)
  k_gemm_tiled<<<dim3(8, 32), 256, 0, stream>>>(enc, HH, Wk, HH, nullptr,
                                                (float*)keysb, BB * SS, HH, HH,
                                                0, 1);
  // encb = bf16(enc)
  k_conv<<<4096, 256, 0, stream>>>(enc, encb, 256, HH);
  // gi0xb = bf16(xs @ W_ih0[:,H:]^T + b_ih0)   (consumes xs)
  k_gemm_tiled<<<dim3(24, 16), 256, 0, stream>>>(xs, EE, Wih0 + HH, HH + EE,
                                                 bih0, (float*)gi0xb,
                                                 TT * BB, H3, EE, 0, 1);
  // recurrent weights -> bf16 (wqb into dead xs region, AFTER gi0x GEMM)
  k_conv<<<1024, 256, 0, stream>>>(Wq, wqb, 256, HH);
  k_conv<<<3072, 256, 0, stream>>>(Wih0, wi0b, 256, HH + EE);  // ctx cols only
  k_conv<<<3072, 256, 0, stream>>>(Whh0, wh0b, 256, HH);
  k_conv<<<3072, 256, 0, stream>>>(Wih1, wi1b, 256, HH);
  k_conv<<<3072, 256, 0, stream>>>(Whh1, wh1b, 256, HH);

  // the whole 64-step recurrence, one launch, fence-free sync
  k_persist<<<NB, 256, 0, stream>>>(keysb, encb, gi0xb, wqb,
                                    wi0b, wh0b, wi1b, wh1b,
                                    wv, vlen, hid + BB * HH,
                                    bhh0, bih1, bhh1,
                                    qpart, scores, ctx, h0A, h0B, outs, bar);

  // logits = outs @ W_out^T + b_out  (fp32, permuted [t*B+b] -> [b,t])
  k_gemm_tiled<<<dim3(250, 16), 256, 0, stream>>>(outs, HH, Wout, HH, bout,
                                                  out, TT * BB, VV, HH, 1, 0);
}

// Round 8
// 7532.199 us; speedup vs baseline: 3.9960x; 1.1416x over previous
//
#include <hip/hip_runtime.h>

// ---------------------------------------------------------------------------
// Seq2SeqAttentionDecoder — round 8: persistent recurrence v3 (qpart removed)
//
// R7 counters: k_persist 6.8ms, FETCH 34MB/step ~= 32MB qpart ldu reads
// (16 partials x full h-row read by ALL 512 blocks) + streams. Weights are
// L2-resident now. Fix:
//  * q-projection owned by slice: P1 reads full h1 row (4KB), computes 64
//    q-cols against L2-resident Wq slice, writes qrow[b][slice]. P2 reads
//    the reduced 4KB qrow. qpart (32MB read + 2MB write /step) deleted.
//    Costs +1 grid barrier/step (5 total).
//  * all row-state ldu/stu accesses packed as 8B relaxed agent atomics
//    (values stable post-barrier -> atomicity across the pair not needed;
//    halves coherent-path instruction count).
// Everything else identical to R7 (fence-free tree barrier, bf16 weights,
// vlen-skip, bf16 keys/enc).
// ---------------------------------------------------------------------------

#define BB 32
#define TT 64
#define SS 128
#define HH 1024
#define EE 512
#define VV 32000
#define H3 3072
#define NEGV (-1000000.0f)
#define NB 512          // persistent grid blocks (2/CU exact residency)

typedef __attribute__((ext_vector_type(8))) unsigned short u16x8;
typedef __attribute__((ext_vector_type(4))) unsigned short u16x4;

__device__ __forceinline__ unsigned short f2bf(float f) {
  unsigned int u = __builtin_bit_cast(unsigned int, f);
  unsigned int r = (u + 0x7FFFu + ((u >> 16) & 1u)) >> 16;   // RNE
  return (unsigned short)r;
}
__device__ __forceinline__ float bfu(unsigned short u) {
  return __builtin_bit_cast(float, (unsigned int)u << 16);
}
__device__ __forceinline__ float sigm(float x) {
  return 1.f / (1.f + __expf(-x));
}
__device__ __forceinline__ float tanhfast(float x) {
  float ax = fabsf(x);
  float e = __expf(2.f * ax);
  float th = 1.f - 2.f / (e + 1.f);
  return copysignf(th, x);
}
__device__ __forceinline__ void fma8(float& acc, u16x8 w, float4 x0, float4 x1) {
  acc = fmaf(bfu(w[0]), x0.x, acc); acc = fmaf(bfu(w[1]), x0.y, acc);
  acc = fmaf(bfu(w[2]), x0.z, acc); acc = fmaf(bfu(w[3]), x0.w, acc);
  acc = fmaf(bfu(w[4]), x1.x, acc); acc = fmaf(bfu(w[5]), x1.y, acc);
  acc = fmaf(bfu(w[6]), x1.z, acc); acc = fmaf(bfu(w[7]), x1.w, acc);
}
// L3-coherent state access (agent-scope relaxed atomics) — no fences needed
__device__ __forceinline__ float ldu(const float* p) {
  return __hip_atomic_load((float*)p, __ATOMIC_RELAXED, __HIP_MEMORY_SCOPE_AGENT);
}
__device__ __forceinline__ void stu(float* p, float v) {
  __hip_atomic_store(p, v, __ATOMIC_RELAXED, __HIP_MEMORY_SCOPE_AGENT);
}
__device__ __forceinline__ float2 ldu2(const float* p) {
  unsigned long long v = __hip_atomic_load(
      (const unsigned long long*)p, __ATOMIC_RELAXED, __HIP_MEMORY_SCOPE_AGENT);
  return __builtin_bit_cast(float2, v);
}

// ---------- init: h0A = hidden[0], zero barrier words ----------
__global__ __launch_bounds__(256) void k_init(const float* __restrict__ hid,
                                              float* __restrict__ h0A,
                                              unsigned* __restrict__ bar) {
  int i = blockIdx.x * 256 + threadIdx.x;
  if (i < BB * HH) h0A[i] = hid[i];
  else if (i < BB * HH + 320) bar[i - BB * HH] = 0u;
}

// ---------- gather xs[r=t*B+b][e] = emb[X[b][t]][e]  (fp32) ----------
__global__ __launch_bounds__(256) void k_gather(const int* __restrict__ X,
                                                const float* __restrict__ emb,
                                                float* __restrict__ xs) {
  int idx = blockIdx.x * 256 + threadIdx.x;
  int r = idx >> 7, c4 = (idx & 127) << 2;
  int td = r >> 5, b = r & 31;
  int tok = X[b * TT + td];
  *(float4*)(xs + (size_t)r * EE + c4) =
      *(const float4*)(emb + (size_t)tok * EE + c4);
}

// ---------- fp32 -> packed bf16 (grid = rows) ----------
__global__ __launch_bounds__(256) void k_conv(const float* __restrict__ src,
                                              unsigned short* __restrict__ dst,
                                              int cols4, int ld) {
  int r = blockIdx.x;
  for (int c = threadIdx.x; c < cols4; c += 256) {
    float4 v = *(const float4*)(src + (size_t)r * ld + (size_t)c * 4);
    ushort4 o;
    o.x = f2bf(v.x); o.y = f2bf(v.y); o.z = f2bf(v.z); o.w = f2bf(v.w);
    *(ushort4*)(dst + (size_t)r * cols4 * 4 + (size_t)c * 4) = o;
  }
}

// ---------- fp32 tiled GEMM (proven): C = A @ W^T (+bias), opt bf16 out ----
__global__ __launch_bounds__(256) void k_gemm_tiled(
    const float* __restrict__ A, int lda,
    const float* __restrict__ W, int ldw,
    const float* __restrict__ bias,
    float* __restrict__ C, int M, int N, int K, int permuteBT, int outBF16) {
  __shared__ float As[16][132];
  __shared__ float Ws[16][132];
  const int m0 = blockIdx.y * 128, n0 = blockIdx.x * 128;
  const int t = threadIdx.x;
  const int tm = t >> 4, tn = t & 15;
  float acc[8][8] = {};
  for (int k0 = 0; k0 < K; k0 += 16) {
#pragma unroll
    for (int qq = 0; qq < 2; ++qq) {
      int f = t * 2 + qq;
      int row = f >> 2, c4 = (f & 3) << 2;
      float4 va = *(const float4*)(A + (size_t)(m0 + row) * lda + k0 + c4);
      As[c4 + 0][row] = va.x; As[c4 + 1][row] = va.y;
      As[c4 + 2][row] = va.z; As[c4 + 3][row] = va.w;
      float4 vw = *(const float4*)(W + (size_t)(n0 + row) * ldw + k0 + c4);
      Ws[c4 + 0][row] = vw.x; Ws[c4 + 1][row] = vw.y;
      Ws[c4 + 2][row] = vw.z; Ws[c4 + 3][row] = vw.w;
    }
    __syncthreads();
#pragma unroll
    for (int k = 0; k < 16; ++k) {
      float a[8], w[8];
      *(float4*)&a[0] = *(const float4*)&As[k][tm * 8];
      *(float4*)&a[4] = *(const float4*)&As[k][tm * 8 + 4];
      *(float4*)&w[0] = *(const float4*)&Ws[k][tn * 8];
      *(float4*)&w[4] = *(const float4*)&Ws[k][tn * 8 + 4];
#pragma unroll
      for (int i = 0; i < 8; ++i)
#pragma unroll
        for (int j = 0; j < 8; ++j) acc[i][j] = fmaf(a[i], w[j], acc[i][j]);
    }
    __syncthreads();
  }
#pragma unroll
  for (int i = 0; i < 8; ++i) {
    int m = m0 + tm * 8 + i;
    size_t rowoff = permuteBT ? ((size_t)((m & 31) * TT + (m >> 5))) * N
                              : (size_t)m * N;
#pragma unroll
    for (int jj = 0; jj < 2; ++jj) {
      int n = n0 + tn * 8 + jj * 4;
      float4 v;
      v.x = acc[i][jj * 4 + 0]; v.y = acc[i][jj * 4 + 1];
      v.z = acc[i][jj * 4 + 2]; v.w = acc[i][jj * 4 + 3];
      if (bias) { v.x += bias[n]; v.y += bias[n + 1];
                  v.z += bias[n + 2]; v.w += bias[n + 3]; }
      if (outBF16) {
        ushort4 o;
        o.x = f2bf(v.x); o.y = f2bf(v.y); o.z = f2bf(v.z); o.w = f2bf(v.w);
        *(ushort4*)((unsigned short*)C + rowoff + n) = o;
      } else {
        *(float4*)(C + rowoff + n) = v;
      }
    }
  }
}

// ---------- gates + GRU, one layer. block=(b, sl); strided-k 4-thread split --
__device__ __forceinline__ void gru_phase(
    int sl, int t, float* shmx, float* shmy,
    const float* __restrict__ xg, const float* __restrict__ hg,
    const unsigned short* __restrict__ wi, const unsigned short* __restrict__ wh,
    const unsigned short* __restrict__ gixrow, const float* __restrict__ bih,
    const float* __restrict__ bhh, float* __restrict__ hdst) {
  {
    const int i4 = t * 4;
    float2 xa = ldu2(xg + i4), xb = ldu2(xg + i4 + 2);
    float2 ya = ldu2(hg + i4), yb = ldu2(hg + i4 + 2);
    *(float2*)(shmx + i4) = xa; *(float2*)(shmx + i4 + 2) = xb;
    *(float2*)(shmy + i4) = ya; *(float2*)(shmy + i4 + 2) = yb;
  }
  __syncthreads();
  const int nl = t >> 2, q4 = t & 3;
  const int n = sl * 64 + nl;
  const unsigned short* wr = wi + (size_t)n * HH + q4 * 8;
  const unsigned short* hr = wh + (size_t)n * HH + q4 * 8;
  float air = 0, aiz = 0, ain = 0, ahr = 0, ahz = 0, ahn = 0;
#pragma unroll 2
  for (int j = 0; j < 32; ++j) {
    const int k = q4 * 8 + j * 32;
    float4 x0 = *(const float4*)(shmx + k);
    float4 x1 = *(const float4*)(shmx + k + 4);
    float4 y0 = *(const float4*)(shmy + k);
    float4 y1 = *(const float4*)(shmy + k + 4);
    const unsigned short* wj = wr + j * 32;
    const unsigned short* hj = hr + j * 32;
    fma8(air, *(const u16x8*)(wj),           x0, x1);
    fma8(aiz, *(const u16x8*)(wj + 1048576), x0, x1);
    fma8(ain, *(const u16x8*)(wj + 2097152), x0, x1);
    fma8(ahr, *(const u16x8*)(hj),           y0, y1);
    fma8(ahz, *(const u16x8*)(hj + 1048576), y0, y1);
    fma8(ahn, *(const u16x8*)(hj + 2097152), y0, y1);
  }
  air += __shfl_xor(air, 1); air += __shfl_xor(air, 2);
  aiz += __shfl_xor(aiz, 1); aiz += __shfl_xor(aiz, 2);
  ain += __shfl_xor(ain, 1); ain += __shfl_xor(ain, 2);
  ahr += __shfl_xor(ahr, 1); ahr += __shfl_xor(ahr, 2);
  ahz += __shfl_xor(ahz, 1); ahz += __shfl_xor(ahz, 2);
  ahn += __shfl_xor(ahn, 1); ahn += __shfl_xor(ahn, 2);
  if (q4 == 0) {
    float gr = air, gz = aiz, gn = ain;
    if (gixrow) {
      gr += bfu(gixrow[n]);
      gz += bfu(gixrow[HH + n]);
      gn += bfu(gixrow[2 * HH + n]);
    }
    if (bih) { gr += bih[n]; gz += bih[HH + n]; gn += bih[2 * HH + n]; }
    float h_r = ahr + bhh[n], h_z = ahz + bhh[HH + n], h_n = ahn + bhh[2 * HH + n];
    float r = sigm(gr + h_r);
    float z = sigm(gz + h_z);
    float nn = tanhfast(gn + r * h_n);
    float hv = (1.f - z) * nn + z * shmy[n];
    stu(hdst + n, hv);
  }
}

// ---------- the persistent recurrence kernel (fence-free) ----------
__global__ __launch_bounds__(256, 2) void k_persist(
    const unsigned short* __restrict__ keysb,
    const unsigned short* __restrict__ encb,
    const unsigned short* __restrict__ gi0xb,
    const unsigned short* __restrict__ wqb,
    const unsigned short* __restrict__ wi0, const unsigned short* __restrict__ wh0,
    const unsigned short* __restrict__ wi1, const unsigned short* __restrict__ wh1,
    const float* __restrict__ wv, const int* __restrict__ vlen,
    const float* __restrict__ hid1,
    const float* __restrict__ bhh0, const float* __restrict__ bih1,
    const float* __restrict__ bhh1,
    float* __restrict__ qrow, float* __restrict__ scores,
    float* __restrict__ ctx,
    float* __restrict__ h0A, float* __restrict__ h0B, float* __restrict__ outs,
    unsigned* __restrict__ bar) {
  __shared__ float shm[2688];   // [0,1024) x | [1024,2048) y | [2048,2688) aux
  float* shmx  = shm;
  float* shmy  = shm + 1024;
  float* aux   = shm + 2048;    // 128 scores + 512 partials
  const int bid = blockIdx.x, t = threadIdx.x;
  const int b = bid >> 4, sl = bid & 15;
  const int vb = vlen[b];       // 1..127; rows s >= vb contribute exactly 0
  unsigned* root = bar + 256;
  unsigned* rel  = bar + 288;
  unsigned ep = 0;

#define GBAR() do { ++ep; __syncthreads();                                     \
    if (t == 0) {                                                              \
      unsigned prev = __hip_atomic_fetch_add(bar + (bid & 7) * 32, 1u,         \
                        __ATOMIC_RELAXED, __HIP_MEMORY_SCOPE_AGENT);           \
      if (prev == ep * 64u - 1u) {                                             \
        unsigned pr = __hip_atomic_fetch_add(root, 1u,                         \
                        __ATOMIC_RELAXED, __HIP_MEMORY_SCOPE_AGENT);           \
        if (pr == ep * 8u - 1u)                                                \
          __hip_atomic_store(rel, ep, __ATOMIC_RELAXED,                        \
                             __HIP_MEMORY_SCOPE_AGENT);                        \
      }                                                                        \
      while (__hip_atomic_load(rel, __ATOMIC_RELAXED,                          \
                               __HIP_MEMORY_SCOPE_AGENT) < ep)                 \
        __builtin_amdgcn_s_sleep(1);                                           \
      asm volatile("" ::: "memory");                                           \
    }                                                                          \
    __syncthreads(); } while (0)

  for (int td = 0; td < TT; ++td) {
    const float* h1old = td ? outs + (size_t)(td - 1) * BB * HH : hid1;
    const float* h0old = (td & 1) ? h0B : h0A;
    float*       h0new = (td & 1) ? h0A : h0B;

    // ---- P1: qrow[b][slice] = h1old(full row) @ Wq[slice]^T ----
    {
      const int i4 = t * 4;
      if (td == 0) {
        *(float4*)(shmx + i4) = *(const float4*)(hid1 + b * HH + i4);
      } else {
        const float* hr = h1old + b * HH;
        float2 a = ldu2(hr + i4), c = ldu2(hr + i4 + 2);
        *(float2*)(shmx + i4) = a; *(float2*)(shmx + i4 + 2) = c;
      }
      __syncthreads();
      const int nl = t >> 2, q4 = t & 3;
      const int n = sl * 64 + nl;
      const unsigned short* wr = wqb + (size_t)n * HH + q4 * 8;
      float acc = 0;
#pragma unroll 4
      for (int j = 0; j < 32; ++j) {
        const int k = q4 * 8 + j * 32;
        float4 x0 = *(const float4*)(shmx + k);
        float4 x1 = *(const float4*)(shmx + k + 4);
        fma8(acc, *(const u16x8*)(wr + j * 32), x0, x1);
      }
      acc += __shfl_xor(acc, 1); acc += __shfl_xor(acc, 2);
      if (q4 == 0) stu(qrow + b * HH + n, acc);
    }
    GBAR();

    // ---- P2: scores[b][s] = sum_h tanh(q+keys)*wv (8 s per block) ----
    {
      const int i4 = t * 4;
      float2 a = ldu2(qrow + b * HH + i4);
      float2 c = ldu2(qrow + b * HH + i4 + 2);
      *(float2*)(shmx + i4) = a; *(float2*)(shmx + i4 + 2) = c;
      __syncthreads();
      const int s_loc = t >> 5, g = t & 31;
      const int s = sl * 8 + s_loc;
      float acc = 0;
      if (s < vb) {                        // uniform per 32-lane half
        const unsigned short* kr = keysb + (size_t)(b * SS + s) * HH;
#pragma unroll
        for (int kk = 0; kk < 8; ++kk) {
          const int h = (g + kk * 32) * 4;
          float4 qv = *(const float4*)(shmx + h);
          u16x4 kv = *(const u16x4*)(kr + h);
          float4 wvv = *(const float4*)(wv + h);
          acc = fmaf(tanhfast(qv.x + bfu(kv[0])), wvv.x, acc);
          acc = fmaf(tanhfast(qv.y + bfu(kv[1])), wvv.y, acc);
          acc = fmaf(tanhfast(qv.z + bfu(kv[2])), wvv.z, acc);
          acc = fmaf(tanhfast(qv.w + bfu(kv[3])), wvv.w, acc);
        }
        acc += __shfl_xor(acc, 1); acc += __shfl_xor(acc, 2);
        acc += __shfl_xor(acc, 4); acc += __shfl_xor(acc, 8);
        acc += __shfl_xor(acc, 16);
      }
      if (g == 0) stu(scores + b * SS + s, (s < vb) ? acc : NEGV);
    }
    GBAR();

    // ---- P3: softmax + ctx slice (64 c-columns, bf16 enc, vlen-clamped) ----
    {
      if (t < SS) aux[t] = ldu(scores + b * SS + t);
      __syncthreads();
      float mx = aux[0];
      for (int s = 1; s < vb; ++s) mx = fmaxf(mx, aux[s]);
      float p = (t < SS) ? __expf(aux[t] - mx) : 0.f;   // s>=vb -> exp(NEG)=0
      __syncthreads();
      if (t < SS) aux[t] = p;
      __syncthreads();
      float sum = 0;
      for (int s = 0; s < vb; ++s) sum += aux[s];
      const float inv = 1.f / sum;
      const int cp = t & 31, sg = t >> 5;   // 32 col-pairs x 8 s-groups(16 s)
      const unsigned short* eb = encb + (size_t)b * SS * HH + sl * 64 + cp * 2;
      float a0 = 0, a1 = 0;
      const int send = min((sg + 1) * 16, vb);
      for (int s = sg * 16; s < send; ++s) {
        unsigned e2 = *(const unsigned*)(eb + (size_t)s * HH);
        float pp = aux[s];
        a0 = fmaf(pp, bfu((unsigned short)(e2 & 0xffffu)), a0);
        a1 = fmaf(pp, bfu((unsigned short)(e2 >> 16)), a1);
      }
      aux[SS + sg * 64 + cp * 2]     = a0;
      aux[SS + sg * 64 + cp * 2 + 1] = a1;
      __syncthreads();
      if (t < 64) {
        float v = 0;
#pragma unroll
        for (int g2 = 0; g2 < 8; ++g2) v += aux[SS + g2 * 64 + t];
        stu(ctx + b * HH + sl * 64 + t, v * inv);
      }
    }
    GBAR();

    // ---- P4: layer-0 gates + GRU -> h0new ----
    gru_phase(sl, t, shmx, shmy, ctx + b * HH, h0old + b * HH, wi0, wh0,
              gi0xb + ((size_t)td * BB + b) * H3, nullptr, bhh0,
              h0new + b * HH);
    GBAR();

    // ---- P5: layer-1 gates + GRU -> outs[td] ----
    gru_phase(sl, t, shmx, shmy, h0new + b * HH, h1old + b * HH, wi1, wh1,
              nullptr, bih1, bhh1, outs + (size_t)td * BB * HH + b * HH);
    GBAR();
  }
#undef GBAR
}

// ---------------------------------------------------------------------------
extern "C" void kernel_launch(void* const* d_in, const int* in_sizes, int n_in,
                              void* d_out, int out_size, void* d_ws,
                              size_t ws_size, hipStream_t stream) {
  const int*   X    = (const int*)  d_in[0];
  const float* enc  = (const float*)d_in[1];
  const float* hid  = (const float*)d_in[2];
  const int*   vlen = (const int*)  d_in[3];
  const float* emb  = (const float*)d_in[4];
  const float* Wq   = (const float*)d_in[5];
  const float* Wk   = (const float*)d_in[6];
  const float* wv   = (const float*)d_in[7];
  const float* Wih0 = (const float*)d_in[8];
  const float* Whh0 = (const float*)d_in[9];
  const float* bih0 = (const float*)d_in[10];
  const float* bhh0 = (const float*)d_in[11];
  const float* Wih1 = (const float*)d_in[12];
  const float* Whh1 = (const float*)d_in[13];
  const float* bih1 = (const float*)d_in[14];
  const float* bhh1 = (const float*)d_in[15];
  const float* Wout = (const float*)d_in[16];
  const float* bout = (const float*)d_in[17];
  float* out = (float*)d_out;

  // ---- workspace (float offsets) ----
  float* ws = (float*)d_ws;
  unsigned short* wi0b  = (unsigned short*)ws;              // 4 gate mats, bf16
  unsigned short* wh0b  = wi0b + (size_t)3145728;
  unsigned short* wi1b  = wh0b + (size_t)3145728;
  unsigned short* wh1b  = wi1b + (size_t)3145728;
  float*          outs  = ws + 6291456;                     // 2,097,152
  float*          xs    = ws + 8388608;                     // 1,048,576 (dead after gi0x)
  unsigned short* wqb   = (unsigned short*)xs;              // alias, post-gi0x
  unsigned short* gi0xb = (unsigned short*)(ws + 9437184);  // 3,145,728 f worth
  unsigned short* keysb = (unsigned short*)(ws + 12582912); // 2,097,152 f worth
  unsigned short* encb  = (unsigned short*)(ws + 14680064); // 2,097,152 f worth
  float*          qrow  = ws + 16777216;                    //    32,768
  float*          h0A   = ws + 16809984;                    //    32,768
  float*          h0B   = ws + 16842752;                    //    32,768
  float*          ctx   = ws + 16875520;                    //    32,768
  float*          scores= ws + 16908288;                    //     4,096
  unsigned*       bar   = (unsigned*)(ws + 16912384);       //       320 u

  k_init<<<130, 256, 0, stream>>>(hid, h0A, bar);
  k_gather<<<1024, 256, 0, stream>>>(X, emb, xs);
  // keysb = bf16(enc @ Wk^T)
  k_gemm_tiled<<<dim3(8, 32), 256, 0, stream>>>(enc, HH, Wk, HH, nullptr,
                                                (float*)keysb, BB * SS, HH, HH,
                                                0, 1);
  // encb = bf16(enc)
  k_conv<<<4096, 256, 0, stream>>>(enc, encb, 256, HH);
  // gi0xb = bf16(xs @ W_ih0[:,H:]^T + b_ih0)   (consumes xs)
  k_gemm_tiled<<<dim3(24, 16), 256, 0, stream>>>(xs, EE, Wih0 + HH, HH + EE,
                                                 bih0, (float*)gi0xb,
                                                 TT * BB, H3, EE, 0, 1);
  // recurrent weights -> bf16 (wqb into dead xs region, AFTER gi0x GEMM)
  k_conv<<<1024, 256, 0, stream>>>(Wq, wqb, 256, HH);
  k_conv<<<3072, 256, 0, stream>>>(Wih0, wi0b, 256, HH + EE);  // ctx cols only
  k_conv<<<3072, 256, 0, stream>>>(Whh0, wh0b, 256, HH);
  k_conv<<<3072, 256, 0, stream>>>(Wih1, wi1b, 256, HH);
  k_conv<<<3072, 256, 0, stream>>>(Whh1, wh1b, 256, HH);

  // the whole 64-step recurrence, one launch, fence-free sync
  k_persist<<<NB, 256, 0, stream>>>(keysb, encb, gi0xb, wqb,
                                    wi0b, wh0b, wi1b, wh1b,
                                    wv, vlen, hid + BB * HH,
                                    bhh0, bih1, bhh1,
                                    qrow, scores, ctx, h0A, h0B, outs, bar);

  // logits = outs @ W_out^T + b_out  (fp32, permuted [t*B+b] -> [b,t])
  k_gemm_tiled<<<dim3(250, 16), 256, 0, stream>>>(outs, HH, Wout, HH, bout,
                                                  out, TT * BB, VV, HH, 1, 0);
}

// Round 9
// 5902.990 us; speedup vs baseline: 5.0989x; 1.2760x over previous
//
#include <hip/hip_runtime.h>

// ---------------------------------------------------------------------------
// Seq2SeqAttentionDecoder — round 9
//  * streams (keysb/encb/gi0xb) read NON-TEMPORAL -> stop evicting weights;
//    per-XCD resident set = gates 3.14MB + wq 0.25MB < 4MB L2.
//  * ALL cross-block state bf16 (h0A/h0B/h1/outs/ctx/qrow): halves ldu traffic.
//  * logits GEMM -> MFMA bf16 (m97 structure), isolated A/B of R2's regression;
//    Wout converted to bf16 AFTER the loop into the dead weight/stream overlay.
// ---------------------------------------------------------------------------

#define BB 32
#define TT 64
#define SS 128
#define HH 1024
#define EE 512
#define VV 32000
#define H3 3072
#define NEGV (-1000000.0f)
#define NB 512          // persistent grid blocks (2/CU exact residency)

typedef __attribute__((ext_vector_type(8))) unsigned short u16x8;
typedef __attribute__((ext_vector_type(4))) unsigned short u16x4;
typedef __attribute__((ext_vector_type(8))) short s16x8;
typedef __attribute__((ext_vector_type(4))) float f32x4;

__device__ __forceinline__ unsigned short f2bf(float f) {
  unsigned int u = __builtin_bit_cast(unsigned int, f);
  unsigned int r = (u + 0x7FFFu + ((u >> 16) & 1u)) >> 16;   // RNE
  return (unsigned short)r;
}
__device__ __forceinline__ float bfu(unsigned short u) {
  return __builtin_bit_cast(float, (unsigned int)u << 16);
}
__device__ __forceinline__ float sigm(float x) {
  return 1.f / (1.f + __expf(-x));
}
__device__ __forceinline__ float tanhfast(float x) {
  float ax = fabsf(x);
  float e = __expf(2.f * ax);
  float th = 1.f - 2.f / (e + 1.f);
  return copysignf(th, x);
}
__device__ __forceinline__ void fma8(float& acc, u16x8 w, float4 x0, float4 x1) {
  acc = fmaf(bfu(w[0]), x0.x, acc); acc = fmaf(bfu(w[1]), x0.y, acc);
  acc = fmaf(bfu(w[2]), x0.z, acc); acc = fmaf(bfu(w[3]), x0.w, acc);
  acc = fmaf(bfu(w[4]), x1.x, acc); acc = fmaf(bfu(w[5]), x1.y, acc);
  acc = fmaf(bfu(w[6]), x1.z, acc); acc = fmaf(bfu(w[7]), x1.w, acc);
}
// L3-coherent state access (agent-scope relaxed atomics) — no fences
__device__ __forceinline__ float ldu(const float* p) {
  return __hip_atomic_load((float*)p, __ATOMIC_RELAXED, __HIP_MEMORY_SCOPE_AGENT);
}
__device__ __forceinline__ void stu(float* p, float v) {
  __hip_atomic_store(p, v, __ATOMIC_RELAXED, __HIP_MEMORY_SCOPE_AGENT);
}
__device__ __forceinline__ float4 ldu_bf4(const unsigned short* p) {
  unsigned long long v = __hip_atomic_load(
      (const unsigned long long*)p, __ATOMIC_RELAXED, __HIP_MEMORY_SCOPE_AGENT);
  float4 r;
  r.x = bfu((unsigned short)(v & 0xffffu));
  r.y = bfu((unsigned short)((v >> 16) & 0xffffu));
  r.z = bfu((unsigned short)((v >> 32) & 0xffffu));
  r.w = bfu((unsigned short)((v >> 48) & 0xffffu));
  return r;
}
__device__ __forceinline__ void stu16(unsigned short* p, unsigned short v) {
  __hip_atomic_store(p, v, __ATOMIC_RELAXED, __HIP_MEMORY_SCOPE_AGENT);
}

// ---------- init: h0A/h1i = bf16(hidden), zero barrier words ----------
__global__ __launch_bounds__(256) void k_init(const float* __restrict__ hid,
                                              unsigned short* __restrict__ h0A,
                                              unsigned short* __restrict__ h1i,
                                              unsigned* __restrict__ bar) {
  int i = blockIdx.x * 256 + threadIdx.x;
  if (i < BB * HH) h0A[i] = f2bf(hid[i]);
  else if (i < 2 * BB * HH) h1i[i - BB * HH] = f2bf(hid[i]);
  else if (i < 2 * BB * HH + 320) bar[i - 2 * BB * HH] = 0u;
}

// ---------- gather xs[r=t*B+b][e] = emb[X[b][t]][e]  (fp32) ----------
__global__ __launch_bounds__(256) void k_gather(const int* __restrict__ X,
                                                const float* __restrict__ emb,
                                                float* __restrict__ xs) {
  int idx = blockIdx.x * 256 + threadIdx.x;
  int r = idx >> 7, c4 = (idx & 127) << 2;
  int td = r >> 5, b = r & 31;
  int tok = X[b * TT + td];
  *(float4*)(xs + (size_t)r * EE + c4) =
      *(const float4*)(emb + (size_t)tok * EE + c4);
}

// ---------- fp32 -> packed bf16 (grid = rows) ----------
__global__ __launch_bounds__(256) void k_conv(const float* __restrict__ src,
                                              unsigned short* __restrict__ dst,
                                              int cols4, int ld) {
  int r = blockIdx.x;
  for (int c = threadIdx.x; c < cols4; c += 256) {
    float4 v = *(const float4*)(src + (size_t)r * ld + (size_t)c * 4);
    ushort4 o;
    o.x = f2bf(v.x); o.y = f2bf(v.y); o.z = f2bf(v.z); o.w = f2bf(v.w);
    *(ushort4*)(dst + (size_t)r * cols4 * 4 + (size_t)c * 4) = o;
  }
}

// ---------- fp32 tiled GEMM (proven): C = A @ W^T (+bias), opt bf16 out ----
__global__ __launch_bounds__(256) void k_gemm_tiled(
    const float* __restrict__ A, int lda,
    const float* __restrict__ W, int ldw,
    const float* __restrict__ bias,
    float* __restrict__ C, int M, int N, int K, int permuteBT, int outBF16) {
  __shared__ float As[16][132];
  __shared__ float Ws[16][132];
  const int m0 = blockIdx.y * 128, n0 = blockIdx.x * 128;
  const int t = threadIdx.x;
  const int tm = t >> 4, tn = t & 15;
  float acc[8][8] = {};
  for (int k0 = 0; k0 < K; k0 += 16) {
#pragma unroll
    for (int qq = 0; qq < 2; ++qq) {
      int f = t * 2 + qq;
      int row = f >> 2, c4 = (f & 3) << 2;
      float4 va = *(const float4*)(A + (size_t)(m0 + row) * lda + k0 + c4);
      As[c4 + 0][row] = va.x; As[c4 + 1][row] = va.y;
      As[c4 + 2][row] = va.z; As[c4 + 3][row] = va.w;
      float4 vw = *(const float4*)(W + (size_t)(n0 + row) * ldw + k0 + c4);
      Ws[c4 + 0][row] = vw.x; Ws[c4 + 1][row] = vw.y;
      Ws[c4 + 2][row] = vw.z; Ws[c4 + 3][row] = vw.w;
    }
    __syncthreads();
#pragma unroll
    for (int k = 0; k < 16; ++k) {
      float a[8], w[8];
      *(float4*)&a[0] = *(const float4*)&As[k][tm * 8];
      *(float4*)&a[4] = *(const float4*)&As[k][tm * 8 + 4];
      *(float4*)&w[0] = *(const float4*)&Ws[k][tn * 8];
      *(float4*)&w[4] = *(const float4*)&Ws[k][tn * 8 + 4];
#pragma unroll
      for (int i = 0; i < 8; ++i)
#pragma unroll
        for (int j = 0; j < 8; ++j) acc[i][j] = fmaf(a[i], w[j], acc[i][j]);
    }
    __syncthreads();
  }
#pragma unroll
  for (int i = 0; i < 8; ++i) {
    int m = m0 + tm * 8 + i;
    size_t rowoff = permuteBT ? ((size_t)((m & 31) * TT + (m >> 5))) * N
                              : (size_t)m * N;
#pragma unroll
    for (int jj = 0; jj < 2; ++jj) {
      int n = n0 + tn * 8 + jj * 4;
      float4 v;
      v.x = acc[i][jj * 4 + 0]; v.y = acc[i][jj * 4 + 1];
      v.z = acc[i][jj * 4 + 2]; v.w = acc[i][jj * 4 + 3];
      if (bias) { v.x += bias[n]; v.y += bias[n + 1];
                  v.z += bias[n + 2]; v.w += bias[n + 3]; }
      if (outBF16) {
        ushort4 o;
        o.x = f2bf(v.x); o.y = f2bf(v.y); o.z = f2bf(v.z); o.w = f2bf(v.w);
        *(ushort4*)((unsigned short*)C + rowoff + n) = o;
      } else {
        *(float4*)(C + rowoff + n) = v;
      }
    }
  }
}

// ---------- bf16 MFMA GEMM (m97 structure): C[M,N] = A@W^T (+bias) ----------
__global__ __launch_bounds__(256) void k_gemm_mfma(
    const unsigned short* __restrict__ A, const unsigned short* __restrict__ W,
    const float* __restrict__ bias, float* __restrict__ C,
    int M, int N, int K, int permuteBT) {
  __shared__ unsigned short As[128 * 32];
  __shared__ unsigned short Bs[128 * 32];
  const int m0 = blockIdx.y * 128, n0 = blockIdx.x * 128;
  const int t = threadIdx.x;
  const int lane = t & 63, w = t >> 6;
  const int wr = w >> 1, wc = w & 1;
  const int fr = lane & 15, fq = lane >> 4;
  const int srow = t >> 2;
  const int scol = (t & 3) * 8;
  f32x4 acc[4][4] = {};
  for (int k0 = 0; k0 < K; k0 += 32) {
#pragma unroll
    for (int i = 0; i < 2; ++i) {
      __builtin_amdgcn_global_load_lds(
          (const __attribute__((address_space(1))) void*)(A + (size_t)(m0 + i * 64 + srow) * K + k0 + scol),
          (__attribute__((address_space(3))) void*)((char*)As + i * 4096 + w * 1024),
          16, 0, 0);
      __builtin_amdgcn_global_load_lds(
          (const __attribute__((address_space(1))) void*)(W + (size_t)(n0 + i * 64 + srow) * K + k0 + scol),
          (__attribute__((address_space(3))) void*)((char*)Bs + i * 4096 + w * 1024),
          16, 0, 0);
    }
    __syncthreads();
    s16x8 af[4], bf[4];
#pragma unroll
    for (int mi = 0; mi < 4; ++mi)
      af[mi] = *(const s16x8*)(As + (wr * 64 + mi * 16 + fr) * 32 + fq * 8);
#pragma unroll
    for (int ni = 0; ni < 4; ++ni)
      bf[ni] = *(const s16x8*)(Bs + (wc * 64 + ni * 16 + fr) * 32 + fq * 8);
#pragma unroll
    for (int mi = 0; mi < 4; ++mi)
#pragma unroll
      for (int ni = 0; ni < 4; ++ni)
        acc[mi][ni] = __builtin_amdgcn_mfma_f32_16x16x32_bf16(
            af[mi], bf[ni], acc[mi][ni], 0, 0, 0);
    __syncthreads();
  }
#pragma unroll
  for (int mi = 0; mi < 4; ++mi) {
#pragma unroll
    for (int ni = 0; ni < 4; ++ni) {
      int gc = n0 + wc * 64 + ni * 16 + fr;
      float bv = bias ? bias[gc] : 0.f;
#pragma unroll
      for (int j = 0; j < 4; ++j) {
        int gm = m0 + wr * 64 + mi * 16 + fq * 4 + j;
        size_t ro = permuteBT ? ((size_t)((gm & 31) * TT + (gm >> 5))) * N
                              : (size_t)gm * N;
        C[ro + gc] = acc[mi][ni][j] + bv;
      }
    }
  }
}

// ---------- gates + GRU, one layer; bf16 state rows, strided-k split ----------
__device__ __forceinline__ void gru_phase(
    int sl, int t, float* shmx, float* shmy,
    const unsigned short* __restrict__ xg, const unsigned short* __restrict__ hg,
    const unsigned short* __restrict__ wi, const unsigned short* __restrict__ wh,
    const unsigned short* __restrict__ gixrow, const float* __restrict__ bih,
    const float* __restrict__ bhh, unsigned short* __restrict__ hdst) {
  const int i4 = t * 4;
  *(float4*)(shmx + i4) = ldu_bf4(xg + i4);
  *(float4*)(shmy + i4) = ldu_bf4(hg + i4);
  __syncthreads();
  const int nl = t >> 2, q4 = t & 3;
  const int n = sl * 64 + nl;
  const unsigned short* wr = wi + (size_t)n * HH + q4 * 8;
  const unsigned short* hr = wh + (size_t)n * HH + q4 * 8;
  float air = 0, aiz = 0, ain = 0, ahr = 0, ahz = 0, ahn = 0;
#pragma unroll 2
  for (int j = 0; j < 32; ++j) {
    const int k = q4 * 8 + j * 32;
    float4 x0 = *(const float4*)(shmx + k);
    float4 x1 = *(const float4*)(shmx + k + 4);
    float4 y0 = *(const float4*)(shmy + k);
    float4 y1 = *(const float4*)(shmy + k + 4);
    const unsigned short* wj = wr + j * 32;
    const unsigned short* hj = hr + j * 32;
    fma8(air, *(const u16x8*)(wj),           x0, x1);
    fma8(aiz, *(const u16x8*)(wj + 1048576), x0, x1);
    fma8(ain, *(const u16x8*)(wj + 2097152), x0, x1);
    fma8(ahr, *(const u16x8*)(hj),           y0, y1);
    fma8(ahz, *(const u16x8*)(hj + 1048576), y0, y1);
    fma8(ahn, *(const u16x8*)(hj + 2097152), y0, y1);
  }
  air += __shfl_xor(air, 1); air += __shfl_xor(air, 2);
  aiz += __shfl_xor(aiz, 1); aiz += __shfl_xor(aiz, 2);
  ain += __shfl_xor(ain, 1); ain += __shfl_xor(ain, 2);
  ahr += __shfl_xor(ahr, 1); ahr += __shfl_xor(ahr, 2);
  ahz += __shfl_xor(ahz, 1); ahz += __shfl_xor(ahz, 2);
  ahn += __shfl_xor(ahn, 1); ahn += __shfl_xor(ahn, 2);
  if (q4 == 0) {
    float gr = air, gz = aiz, gn = ain;
    if (gixrow) {
      gr += bfu(__builtin_nontemporal_load(gixrow + n));
      gz += bfu(__builtin_nontemporal_load(gixrow + HH + n));
      gn += bfu(__builtin_nontemporal_load(gixrow + 2 * HH + n));
    }
    if (bih) { gr += bih[n]; gz += bih[HH + n]; gn += bih[2 * HH + n]; }
    float h_r = ahr + bhh[n], h_z = ahz + bhh[HH + n], h_n = ahn + bhh[2 * HH + n];
    float r = sigm(gr + h_r);
    float z = sigm(gz + h_z);
    float nn = tanhfast(gn + r * h_n);
    float hv = (1.f - z) * nn + z * shmy[n];
    stu16(hdst + n, f2bf(hv));
  }
}

// ---------- the persistent recurrence kernel (fence-free) ----------
__global__ __launch_bounds__(256, 2) void k_persist(
    const unsigned short* __restrict__ keysb,
    const unsigned short* __restrict__ encb,
    const unsigned short* __restrict__ gi0xb,
    const unsigned short* __restrict__ wqb,
    const unsigned short* __restrict__ wi0, const unsigned short* __restrict__ wh0,
    const unsigned short* __restrict__ wi1, const unsigned short* __restrict__ wh1,
    const float* __restrict__ wv, const int* __restrict__ vlen,
    const unsigned short* __restrict__ h1i,
    const float* __restrict__ bhh0, const float* __restrict__ bih1,
    const float* __restrict__ bhh1,
    unsigned short* __restrict__ qrowb, float* __restrict__ scores,
    unsigned short* __restrict__ ctxb,
    unsigned short* __restrict__ h0A, unsigned short* __restrict__ h0B,
    unsigned short* __restrict__ outsb,
    unsigned* __restrict__ bar) {
  __shared__ float shm[2688];
  float* shmx  = shm;
  float* shmy  = shm + 1024;
  float* aux   = shm + 2048;
  const int bid = blockIdx.x, t = threadIdx.x;
  const int b = bid >> 4, sl = bid & 15;
  const int vb = vlen[b];
  unsigned* root = bar + 256;
  unsigned* rel  = bar + 288;
  unsigned ep = 0;

#define GBAR() do { ++ep; __syncthreads();                                     \
    if (t == 0) {                                                              \
      unsigned prev = __hip_atomic_fetch_add(bar + (bid & 7) * 32, 1u,         \
                        __ATOMIC_RELAXED, __HIP_MEMORY_SCOPE_AGENT);           \
      if (prev == ep * 64u - 1u) {                                             \
        unsigned pr = __hip_atomic_fetch_add(root, 1u,                         \
                        __ATOMIC_RELAXED, __HIP_MEMORY_SCOPE_AGENT);           \
        if (pr == ep * 8u - 1u)                                                \
          __hip_atomic_store(rel, ep, __ATOMIC_RELAXED,                        \
                             __HIP_MEMORY_SCOPE_AGENT);                        \
      }                                                                        \
      while (__hip_atomic_load(rel, __ATOMIC_RELAXED,                          \
                               __HIP_MEMORY_SCOPE_AGENT) < ep)                 \
        __builtin_amdgcn_s_sleep(1);                                           \
      asm volatile("" ::: "memory");                                           \
    }                                                                          \
    __syncthreads(); } while (0)

  for (int td = 0; td < TT; ++td) {
    const unsigned short* h1old =
        td ? outsb + (size_t)(td - 1) * BB * HH : h1i;
    const unsigned short* h0old = (td & 1) ? h0B : h0A;
    unsigned short*       h0new = (td & 1) ? h0A : h0B;

    // ---- P1: qrow[b][slice] = h1old(full row) @ Wq[slice]^T ----
    {
      const int i4 = t * 4;
      *(float4*)(shmx + i4) = ldu_bf4(h1old + b * HH + i4);
      __syncthreads();
      const int nl = t >> 2, q4 = t & 3;
      const int n = sl * 64 + nl;
      const unsigned short* wr = wqb + (size_t)n * HH + q4 * 8;
      float acc = 0;
#pragma unroll 4
      for (int j = 0; j < 32; ++j) {
        const int k = q4 * 8 + j * 32;
        float4 x0 = *(const float4*)(shmx + k);
        float4 x1 = *(const float4*)(shmx + k + 4);
        fma8(acc, *(const u16x8*)(wr + j * 32), x0, x1);
      }
      acc += __shfl_xor(acc, 1); acc += __shfl_xor(acc, 2);
      if (q4 == 0) stu16(qrowb + b * HH + n, f2bf(acc));
    }
    GBAR();

    // ---- P2: scores[b][s] = sum_h tanh(q+keys)*wv (8 s per block) ----
    {
      const int i4 = t * 4;
      *(float4*)(shmx + i4) = ldu_bf4(qrowb + b * HH + i4);
      __syncthreads();
      const int s_loc = t >> 5, g = t & 31;
      const int s = sl * 8 + s_loc;
      float acc = 0;
      if (s < vb) {
        const unsigned short* kr = keysb + (size_t)(b * SS + s) * HH;
#pragma unroll
        for (int kk = 0; kk < 8; ++kk) {
          const int h = (g + kk * 32) * 4;
          float4 qv = *(const float4*)(shmx + h);
          u16x4 kv = __builtin_nontemporal_load((const u16x4*)(kr + h));
          float4 wvv = *(const float4*)(wv + h);
          acc = fmaf(tanhfast(qv.x + bfu(kv[0])), wvv.x, acc);
          acc = fmaf(tanhfast(qv.y + bfu(kv[1])), wvv.y, acc);
          acc = fmaf(tanhfast(qv.z + bfu(kv[2])), wvv.z, acc);
          acc = fmaf(tanhfast(qv.w + bfu(kv[3])), wvv.w, acc);
        }
        acc += __shfl_xor(acc, 1); acc += __shfl_xor(acc, 2);
        acc += __shfl_xor(acc, 4); acc += __shfl_xor(acc, 8);
        acc += __shfl_xor(acc, 16);
      }
      if (g == 0) stu(scores + b * SS + s, (s < vb) ? acc : NEGV);
    }
    GBAR();

    // ---- P3: softmax + ctx slice (64 c-columns, nt bf16 enc, vlen-clamped) --
    {
      if (t < SS) aux[t] = ldu(scores + b * SS + t);
      __syncthreads();
      float mx = aux[0];
      for (int s = 1; s < vb; ++s) mx = fmaxf(mx, aux[s]);
      float p = (t < SS) ? __expf(aux[t] - mx) : 0.f;
      __syncthreads();
      if (t < SS) aux[t] = p;
      __syncthreads();
      float sum = 0;
      for (int s = 0; s < vb; ++s) sum += aux[s];
      const float inv = 1.f / sum;
      const int cp = t & 31, sg = t >> 5;
      const unsigned short* eb = encb + (size_t)b * SS * HH + sl * 64 + cp * 2;
      float a0 = 0, a1 = 0;
      const int send = min((sg + 1) * 16, vb);
      for (int s = sg * 16; s < send; ++s) {
        unsigned e2 = __builtin_nontemporal_load(
            (const unsigned*)(eb + (size_t)s * HH));
        float pp = aux[s];
        a0 = fmaf(pp, bfu((unsigned short)(e2 & 0xffffu)), a0);
        a1 = fmaf(pp, bfu((unsigned short)(e2 >> 16)), a1);
      }
      aux[SS + sg * 64 + cp * 2]     = a0;
      aux[SS + sg * 64 + cp * 2 + 1] = a1;
      __syncthreads();
      if (t < 64) {
        float v = 0;
#pragma unroll
        for (int g2 = 0; g2 < 8; ++g2) v += aux[SS + g2 * 64 + t];
        stu16(ctxb + b * HH + sl * 64 + t, f2bf(v * inv));
      }
    }
    GBAR();

    // ---- P4: layer-0 gates + GRU -> h0new ----
    gru_phase(sl, t, shmx, shmy, ctxb + b * HH, h0old + b * HH, wi0, wh0,
              gi0xb + ((size_t)td * BB + b) * H3, nullptr, bhh0,
              h0new + b * HH);
    GBAR();

    // ---- P5: layer-1 gates + GRU -> outsb[td] (= h1 state, bf16) ----
    gru_phase(sl, t, shmx, shmy, h0new + b * HH, h1old + b * HH, wi1, wh1,
              nullptr, bih1, bhh1, outsb + (size_t)td * BB * HH + b * HH);
    GBAR();
  }
#undef GBAR
}

// ---------------------------------------------------------------------------
extern "C" void kernel_launch(void* const* d_in, const int* in_sizes, int n_in,
                              void* d_out, int out_size, void* d_ws,
                              size_t ws_size, hipStream_t stream) {
  const int*   X    = (const int*)  d_in[0];
  const float* enc  = (const float*)d_in[1];
  const float* hid  = (const float*)d_in[2];
  const int*   vlen = (const int*)  d_in[3];
  const float* emb  = (const float*)d_in[4];
  const float* Wq   = (const float*)d_in[5];
  const float* Wk   = (const float*)d_in[6];
  const float* wv   = (const float*)d_in[7];
  const float* Wih0 = (const float*)d_in[8];
  const float* Whh0 = (const float*)d_in[9];
  const float* bih0 = (const float*)d_in[10];
  const float* bhh0 = (const float*)d_in[11];
  const float* Wih1 = (const float*)d_in[12];
  const float* Whh1 = (const float*)d_in[13];
  const float* bih1 = (const float*)d_in[14];
  const float* bhh1 = (const float*)d_in[15];
  const float* Wout = (const float*)d_in[16];
  const float* bout = (const float*)d_in[17];
  float* out = (float*)d_out;

  // ---- workspace (float offsets), total ~70.1 MB ----
  // Front region [0 .. 15,204,352 f) is DEAD after k_persist; woutb
  // (bf16 Wout, 16,384,000 f worth) overlays [0 .. 16,384,000 f) post-loop.
  float* ws = (float*)d_ws;
  unsigned short* wi0b  = (unsigned short*)ws;                 // 6.29MB
  unsigned short* wh0b  = wi0b + (size_t)3145728;
  unsigned short* wi1b  = wh0b + (size_t)3145728;
  unsigned short* wh1b  = wi1b + (size_t)3145728;
  unsigned short* wqb   = (unsigned short*)(ws + 6291456);     // 2MB
  unsigned short* gi0xb = (unsigned short*)(ws + 6815744);     // 12.6MB
  unsigned short* keysb = (unsigned short*)(ws + 9961472);     // 8MB
  unsigned short* encb  = (unsigned short*)(ws + 12058624);    // 8MB
  float*          xs    = ws + 14155776;                       // 4MB (dead early)
  unsigned short* woutb = (unsigned short*)ws;                 // overlay post-loop
  unsigned short* outsb = (unsigned short*)(ws + 16384000);    // 4.19MB (h1/outs)
  unsigned short* h0A   = (unsigned short*)(ws + 17432576);
  unsigned short* h0B   = (unsigned short*)(ws + 17448960);
  unsigned short* h1i   = (unsigned short*)(ws + 17465344);
  unsigned short* ctxb  = (unsigned short*)(ws + 17481728);
  unsigned short* qrowb = (unsigned short*)(ws + 17498112);
  float*          scores= ws + 17514496;
  unsigned*       bar   = (unsigned*)(ws + 17518592);

  k_init<<<258, 256, 0, stream>>>(hid, h0A, h1i, bar);
  k_gather<<<1024, 256, 0, stream>>>(X, emb, xs);
  // keysb = bf16(enc @ Wk^T)
  k_gemm_tiled<<<dim3(8, 32), 256, 0, stream>>>(enc, HH, Wk, HH, nullptr,
                                                (float*)keysb, BB * SS, HH, HH,
                                                0, 1);
  // encb = bf16(enc)
  k_conv<<<4096, 256, 0, stream>>>(enc, encb, 256, HH);
  // gi0xb = bf16(xs @ W_ih0[:,H:]^T + b_ih0)   (consumes xs)
  k_gemm_tiled<<<dim3(24, 16), 256, 0, stream>>>(xs, EE, Wih0 + HH, HH + EE,
                                                 bih0, (float*)gi0xb,
                                                 TT * BB, H3, EE, 0, 1);
  // recurrent weights -> bf16
  k_conv<<<1024, 256, 0, stream>>>(Wq, wqb, 256, HH);
  k_conv<<<3072, 256, 0, stream>>>(Wih0, wi0b, 256, HH + EE);  // ctx cols only
  k_conv<<<3072, 256, 0, stream>>>(Whh0, wh0b, 256, HH);
  k_conv<<<3072, 256, 0, stream>>>(Wih1, wi1b, 256, HH);
  k_conv<<<3072, 256, 0, stream>>>(Whh1, wh1b, 256, HH);

  // the whole 64-step recurrence, one launch, fence-free sync
  k_persist<<<NB, 256, 0, stream>>>(keysb, encb, gi0xb, wqb,
                                    wi0b, wh0b, wi1b, wh1b,
                                    wv, vlen, h1i,
                                    bhh0, bih1, bhh1,
                                    qrowb, scores, ctxb, h0A, h0B, outsb, bar);

  // Wout -> bf16 into the now-dead overlay, then MFMA logits GEMM
  k_conv<<<32000, 256, 0, stream>>>(Wout, woutb, 256, HH);
  k_gemm_mfma<<<dim3(250, 16), 256, 0, stream>>>(outsb, woutb, bout, out,
                                                 TT * BB, VV, HH, 1);
}

// Round 10
// 5525.234 us; speedup vs baseline: 5.4475x; 1.0684x over previous
//
#include <hip/hip_runtime.h>

// ---------------------------------------------------------------------------
// Seq2SeqAttentionDecoder — round 10
//  R9 counters: k_persist 5.53ms, VALUBusy 31.7%, 135 GB/s -> sync-bound.
//  Suspect: barrier arrival = 64 serialized same-address atomic RMWs per
//  group word (~6us/barrier x 5/step ~= 30us/step).
//  * GBAR v3: contention-free flag barrier. Arrive = ONE relaxed agent store
//    to bar[bid]; block 0's threads poll all 512 flags; release word.
//  * prologue keys/gi0x GEMMs -> MFMA bf16 (k_gemm_tiled deleted);
//    gather writes bf16 xs directly; Wk / Wih0[:,H:] converted once.
//  Persist phase math/state identical to R9 (bf16 state, nt streams).
// ---------------------------------------------------------------------------

#define BB 32
#define TT 64
#define SS 128
#define HH 1024
#define EE 512
#define VV 32000
#define H3 3072
#define NEGV (-1000000.0f)
#define NB 512          // persistent grid blocks (2/CU exact residency)

typedef __attribute__((ext_vector_type(8))) unsigned short u16x8;
typedef __attribute__((ext_vector_type(4))) unsigned short u16x4;
typedef __attribute__((ext_vector_type(8))) short s16x8;
typedef __attribute__((ext_vector_type(4))) float f32x4;

__device__ __forceinline__ unsigned short f2bf(float f) {
  unsigned int u = __builtin_bit_cast(unsigned int, f);
  unsigned int r = (u + 0x7FFFu + ((u >> 16) & 1u)) >> 16;   // RNE
  return (unsigned short)r;
}
__device__ __forceinline__ float bfu(unsigned short u) {
  return __builtin_bit_cast(float, (unsigned int)u << 16);
}
__device__ __forceinline__ float sigm(float x) {
  return 1.f / (1.f + __expf(-x));
}
__device__ __forceinline__ float tanhfast(float x) {
  float ax = fabsf(x);
  float e = __expf(2.f * ax);
  float th = 1.f - 2.f / (e + 1.f);
  return copysignf(th, x);
}
__device__ __forceinline__ void fma8(float& acc, u16x8 w, float4 x0, float4 x1) {
  acc = fmaf(bfu(w[0]), x0.x, acc); acc = fmaf(bfu(w[1]), x0.y, acc);
  acc = fmaf(bfu(w[2]), x0.z, acc); acc = fmaf(bfu(w[3]), x0.w, acc);
  acc = fmaf(bfu(w[4]), x1.x, acc); acc = fmaf(bfu(w[5]), x1.y, acc);
  acc = fmaf(bfu(w[6]), x1.z, acc); acc = fmaf(bfu(w[7]), x1.w, acc);
}
// L3-coherent state access (agent-scope relaxed atomics) — no fences
__device__ __forceinline__ float ldu(const float* p) {
  return __hip_atomic_load((float*)p, __ATOMIC_RELAXED, __HIP_MEMORY_SCOPE_AGENT);
}
__device__ __forceinline__ void stu(float* p, float v) {
  __hip_atomic_store(p, v, __ATOMIC_RELAXED, __HIP_MEMORY_SCOPE_AGENT);
}
__device__ __forceinline__ float4 ldu_bf4(const unsigned short* p) {
  unsigned long long v = __hip_atomic_load(
      (const unsigned long long*)p, __ATOMIC_RELAXED, __HIP_MEMORY_SCOPE_AGENT);
  float4 r;
  r.x = bfu((unsigned short)(v & 0xffffu));
  r.y = bfu((unsigned short)((v >> 16) & 0xffffu));
  r.z = bfu((unsigned short)((v >> 32) & 0xffffu));
  r.w = bfu((unsigned short)((v >> 48) & 0xffffu));
  return r;
}
__device__ __forceinline__ void stu16(unsigned short* p, unsigned short v) {
  __hip_atomic_store(p, v, __ATOMIC_RELAXED, __HIP_MEMORY_SCOPE_AGENT);
}

// ---------- init: h0A/h1i = bf16(hidden), zero barrier words ----------
__global__ __launch_bounds__(256) void k_init(const float* __restrict__ hid,
                                              unsigned short* __restrict__ h0A,
                                              unsigned short* __restrict__ h1i,
                                              unsigned* __restrict__ bar) {
  int i = blockIdx.x * 256 + threadIdx.x;
  if (i < BB * HH) h0A[i] = f2bf(hid[i]);
  else if (i < 2 * BB * HH) h1i[i - BB * HH] = f2bf(hid[i]);
  else if (i < 2 * BB * HH + 576) bar[i - 2 * BB * HH] = 0u;
}

// ---------- gather xs[r=t*B+b][e] = bf16(emb[X[b][t]][e]) ----------
__global__ __launch_bounds__(256) void k_gather(const int* __restrict__ X,
                                                const float* __restrict__ emb,
                                                unsigned short* __restrict__ xs) {
  int idx = blockIdx.x * 256 + threadIdx.x;
  int r = idx >> 7, c4 = (idx & 127) << 2;
  int td = r >> 5, b = r & 31;
  int tok = X[b * TT + td];
  float4 v = *(const float4*)(emb + (size_t)tok * EE + c4);
  ushort4 o;
  o.x = f2bf(v.x); o.y = f2bf(v.y); o.z = f2bf(v.z); o.w = f2bf(v.w);
  *(ushort4*)(xs + (size_t)r * EE + c4) = o;
}

// ---------- fp32 -> packed bf16 (grid = rows) ----------
__global__ __launch_bounds__(256) void k_conv(const float* __restrict__ src,
                                              unsigned short* __restrict__ dst,
                                              int cols4, int ld) {
  int r = blockIdx.x;
  for (int c = threadIdx.x; c < cols4; c += 256) {
    float4 v = *(const float4*)(src + (size_t)r * ld + (size_t)c * 4);
    ushort4 o;
    o.x = f2bf(v.x); o.y = f2bf(v.y); o.z = f2bf(v.z); o.w = f2bf(v.w);
    *(ushort4*)(dst + (size_t)r * cols4 * 4 + (size_t)c * 4) = o;
  }
}

// ---------- bf16 MFMA GEMM (m97 structure): C[M,N] = A@W^T (+bias) ----------
__global__ __launch_bounds__(256) void k_gemm_mfma(
    const unsigned short* __restrict__ A, const unsigned short* __restrict__ W,
    const float* __restrict__ bias, float* __restrict__ C,
    int M, int N, int K, int permuteBT, int outBF16) {
  __shared__ unsigned short As[128 * 32];
  __shared__ unsigned short Bs[128 * 32];
  const int m0 = blockIdx.y * 128, n0 = blockIdx.x * 128;
  const int t = threadIdx.x;
  const int lane = t & 63, w = t >> 6;
  const int wr = w >> 1, wc = w & 1;
  const int fr = lane & 15, fq = lane >> 4;
  const int srow = t >> 2;
  const int scol = (t & 3) * 8;
  f32x4 acc[4][4] = {};
  for (int k0 = 0; k0 < K; k0 += 32) {
#pragma unroll
    for (int i = 0; i < 2; ++i) {
      __builtin_amdgcn_global_load_lds(
          (const __attribute__((address_space(1))) void*)(A + (size_t)(m0 + i * 64 + srow) * K + k0 + scol),
          (__attribute__((address_space(3))) void*)((char*)As + i * 4096 + w * 1024),
          16, 0, 0);
      __builtin_amdgcn_global_load_lds(
          (const __attribute__((address_space(1))) void*)(W + (size_t)(n0 + i * 64 + srow) * K + k0 + scol),
          (__attribute__((address_space(3))) void*)((char*)Bs + i * 4096 + w * 1024),
          16, 0, 0);
    }
    __syncthreads();
    s16x8 af[4], bf[4];
#pragma unroll
    for (int mi = 0; mi < 4; ++mi)
      af[mi] = *(const s16x8*)(As + (wr * 64 + mi * 16 + fr) * 32 + fq * 8);
#pragma unroll
    for (int ni = 0; ni < 4; ++ni)
      bf[ni] = *(const s16x8*)(Bs + (wc * 64 + ni * 16 + fr) * 32 + fq * 8);
#pragma unroll
    for (int mi = 0; mi < 4; ++mi)
#pragma unroll
      for (int ni = 0; ni < 4; ++ni)
        acc[mi][ni] = __builtin_amdgcn_mfma_f32_16x16x32_bf16(
            af[mi], bf[ni], acc[mi][ni], 0, 0, 0);
    __syncthreads();
  }
#pragma unroll
  for (int mi = 0; mi < 4; ++mi) {
#pragma unroll
    for (int ni = 0; ni < 4; ++ni) {
      int gc = n0 + wc * 64 + ni * 16 + fr;
      float bv = bias ? bias[gc] : 0.f;
#pragma unroll
      for (int j = 0; j < 4; ++j) {
        int gm = m0 + wr * 64 + mi * 16 + fq * 4 + j;
        size_t ro = permuteBT ? ((size_t)((gm & 31) * TT + (gm >> 5))) * N
                              : (size_t)gm * N;
        float v = acc[mi][ni][j] + bv;
        if (outBF16) ((unsigned short*)C)[ro + gc] = f2bf(v);
        else         C[ro + gc] = v;
      }
    }
  }
}

// ---------- gates + GRU, one layer; bf16 state rows, strided-k split ----------
__device__ __forceinline__ void gru_phase(
    int sl, int t, float* shmx, float* shmy,
    const unsigned short* __restrict__ xg, const unsigned short* __restrict__ hg,
    const unsigned short* __restrict__ wi, const unsigned short* __restrict__ wh,
    const unsigned short* __restrict__ gixrow, const float* __restrict__ bih,
    const float* __restrict__ bhh, unsigned short* __restrict__ hdst) {
  const int i4 = t * 4;
  *(float4*)(shmx + i4) = ldu_bf4(xg + i4);
  *(float4*)(shmy + i4) = ldu_bf4(hg + i4);
  __syncthreads();
  const int nl = t >> 2, q4 = t & 3;
  const int n = sl * 64 + nl;
  const unsigned short* wr = wi + (size_t)n * HH + q4 * 8;
  const unsigned short* hr = wh + (size_t)n * HH + q4 * 8;
  float air = 0, aiz = 0, ain = 0, ahr = 0, ahz = 0, ahn = 0;
#pragma unroll 2
  for (int j = 0; j < 32; ++j) {
    const int k = q4 * 8 + j * 32;
    float4 x0 = *(const float4*)(shmx + k);
    float4 x1 = *(const float4*)(shmx + k + 4);
    float4 y0 = *(const float4*)(shmy + k);
    float4 y1 = *(const float4*)(shmy + k + 4);
    const unsigned short* wj = wr + j * 32;
    const unsigned short* hj = hr + j * 32;
    fma8(air, *(const u16x8*)(wj),           x0, x1);
    fma8(aiz, *(const u16x8*)(wj + 1048576), x0, x1);
    fma8(ain, *(const u16x8*)(wj + 2097152), x0, x1);
    fma8(ahr, *(const u16x8*)(hj),           y0, y1);
    fma8(ahz, *(const u16x8*)(hj + 1048576), y0, y1);
    fma8(ahn, *(const u16x8*)(hj + 2097152), y0, y1);
  }
  air += __shfl_xor(air, 1); air += __shfl_xor(air, 2);
  aiz += __shfl_xor(aiz, 1); aiz += __shfl_xor(aiz, 2);
  ain += __shfl_xor(ain, 1); ain += __shfl_xor(ain, 2);
  ahr += __shfl_xor(ahr, 1); ahr += __shfl_xor(ahr, 2);
  ahz += __shfl_xor(ahz, 1); ahz += __shfl_xor(ahz, 2);
  ahn += __shfl_xor(ahn, 1); ahn += __shfl_xor(ahn, 2);
  if (q4 == 0) {
    float gr = air, gz = aiz, gn = ain;
    if (gixrow) {
      gr += bfu(__builtin_nontemporal_load(gixrow + n));
      gz += bfu(__builtin_nontemporal_load(gixrow + HH + n));
      gn += bfu(__builtin_nontemporal_load(gixrow + 2 * HH + n));
    }
    if (bih) { gr += bih[n]; gz += bih[HH + n]; gn += bih[2 * HH + n]; }
    float h_r = ahr + bhh[n], h_z = ahz + bhh[HH + n], h_n = ahn + bhh[2 * HH + n];
    float r = sigm(gr + h_r);
    float z = sigm(gz + h_z);
    float nn = tanhfast(gn + r * h_n);
    float hv = (1.f - z) * nn + z * shmy[n];
    stu16(hdst + n, f2bf(hv));
  }
}

// ---------- the persistent recurrence kernel (fence-free, flag barrier) ----
__global__ __launch_bounds__(256, 2) void k_persist(
    const unsigned short* __restrict__ keysb,
    const unsigned short* __restrict__ encb,
    const unsigned short* __restrict__ gi0xb,
    const unsigned short* __restrict__ wqb,
    const unsigned short* __restrict__ wi0, const unsigned short* __restrict__ wh0,
    const unsigned short* __restrict__ wi1, const unsigned short* __restrict__ wh1,
    const float* __restrict__ wv, const int* __restrict__ vlen,
    const unsigned short* __restrict__ h1i,
    const float* __restrict__ bhh0, const float* __restrict__ bih1,
    const float* __restrict__ bhh1,
    unsigned short* __restrict__ qrowb, float* __restrict__ scores,
    unsigned short* __restrict__ ctxb,
    unsigned short* __restrict__ h0A, unsigned short* __restrict__ h0B,
    unsigned short* __restrict__ outsb,
    unsigned* __restrict__ bar) {
  __shared__ float shm[2688];
  float* shmx  = shm;
  float* shmy  = shm + 1024;
  float* aux   = shm + 2048;
  const int bid = blockIdx.x, t = threadIdx.x;
  const int b = bid >> 4, sl = bid & 15;
  const int vb = vlen[b];
  unsigned* rel = bar + 512;
  unsigned ep = 0;

  // contention-free flag barrier: arrive = 1 relaxed store (no RMW);
  // block 0 observes all 512 flags (2 per thread) then publishes rel.
#define GBAR() do { ++ep; __syncthreads();                                     \
    if (t == 0)                                                                \
      __hip_atomic_store(bar + bid, ep, __ATOMIC_RELAXED,                      \
                         __HIP_MEMORY_SCOPE_AGENT);                            \
    if (bid == 0) {                                                            \
      while (__hip_atomic_load(bar + t, __ATOMIC_RELAXED,                      \
                               __HIP_MEMORY_SCOPE_AGENT) < ep)                 \
        __builtin_amdgcn_s_sleep(1);                                           \
      while (__hip_atomic_load(bar + 256 + t, __ATOMIC_RELAXED,                \
                               __HIP_MEMORY_SCOPE_AGENT) < ep)                 \
        __builtin_amdgcn_s_sleep(1);                                           \
      __syncthreads();                                                         \
      if (t == 0)                                                              \
        __hip_atomic_store(rel, ep, __ATOMIC_RELAXED,                          \
                           __HIP_MEMORY_SCOPE_AGENT);                          \
    } else if (t == 0) {                                                       \
      while (__hip_atomic_load(rel, __ATOMIC_RELAXED,                          \
                               __HIP_MEMORY_SCOPE_AGENT) < ep)                 \
        __builtin_amdgcn_s_sleep(1);                                           \
    }                                                                          \
    __syncthreads(); } while (0)

  for (int td = 0; td < TT; ++td) {
    const unsigned short* h1old =
        td ? outsb + (size_t)(td - 1) * BB * HH : h1i;
    const unsigned short* h0old = (td & 1) ? h0B : h0A;
    unsigned short*       h0new = (td & 1) ? h0A : h0B;

    // ---- P1: qrow[b][slice] = h1old(full row) @ Wq[slice]^T ----
    {
      const int i4 = t * 4;
      *(float4*)(shmx + i4) = ldu_bf4(h1old + b * HH + i4);
      __syncthreads();
      const int nl = t >> 2, q4 = t & 3;
      const int n = sl * 64 + nl;
      const unsigned short* wr = wqb + (size_t)n * HH + q4 * 8;
      float acc = 0;
#pragma unroll 4
      for (int j = 0; j < 32; ++j) {
        const int k = q4 * 8 + j * 32;
        float4 x0 = *(const float4*)(shmx + k);
        float4 x1 = *(const float4*)(shmx + k + 4);
        fma8(acc, *(const u16x8*)(wr + j * 32), x0, x1);
      }
      acc += __shfl_xor(acc, 1); acc += __shfl_xor(acc, 2);
      if (q4 == 0) stu16(qrowb + b * HH + n, f2bf(acc));
    }
    GBAR();

    // ---- P2: scores[b][s] = sum_h tanh(q+keys)*wv (8 s per block) ----
    {
      const int i4 = t * 4;
      *(float4*)(shmx + i4) = ldu_bf4(qrowb + b * HH + i4);
      __syncthreads();
      const int s_loc = t >> 5, g = t & 31;
      const int s = sl * 8 + s_loc;
      float acc = 0;
      if (s < vb) {
        const unsigned short* kr = keysb + (size_t)(b * SS + s) * HH;
#pragma unroll
        for (int kk = 0; kk < 8; ++kk) {
          const int h = (g + kk * 32) * 4;
          float4 qv = *(const float4*)(shmx + h);
          u16x4 kv = __builtin_nontemporal_load((const u16x4*)(kr + h));
          float4 wvv = *(const float4*)(wv + h);
          acc = fmaf(tanhfast(qv.x + bfu(kv[0])), wvv.x, acc);
          acc = fmaf(tanhfast(qv.y + bfu(kv[1])), wvv.y, acc);
          acc = fmaf(tanhfast(qv.z + bfu(kv[2])), wvv.z, acc);
          acc = fmaf(tanhfast(qv.w + bfu(kv[3])), wvv.w, acc);
        }
        acc += __shfl_xor(acc, 1); acc += __shfl_xor(acc, 2);
        acc += __shfl_xor(acc, 4); acc += __shfl_xor(acc, 8);
        acc += __shfl_xor(acc, 16);
      }
      if (g == 0) stu(scores + b * SS + s, (s < vb) ? acc : NEGV);
    }
    GBAR();

    // ---- P3: softmax + ctx slice (64 c-columns, nt bf16 enc, vlen-clamped) --
    {
      if (t < SS) aux[t] = ldu(scores + b * SS + t);
      __syncthreads();
      float mx = aux[0];
      for (int s = 1; s < vb; ++s) mx = fmaxf(mx, aux[s]);
      float p = (t < SS) ? __expf(aux[t] - mx) : 0.f;
      __syncthreads();
      if (t < SS) aux[t] = p;
      __syncthreads();
      float sum = 0;
      for (int s = 0; s < vb; ++s) sum += aux[s];
      const float inv = 1.f / sum;
      const int cp = t & 31, sg = t >> 5;
      const unsigned short* eb = encb + (size_t)b * SS * HH + sl * 64 + cp * 2;
      float a0 = 0, a1 = 0;
      const int send = min((sg + 1) * 16, vb);
      for (int s = sg * 16; s < send; ++s) {
        unsigned e2 = __builtin_nontemporal_load(
            (const unsigned*)(eb + (size_t)s * HH));
        float pp = aux[s];
        a0 = fmaf(pp, bfu((unsigned short)(e2 & 0xffffu)), a0);
        a1 = fmaf(pp, bfu((unsigned short)(e2 >> 16)), a1);
      }
      aux[SS + sg * 64 + cp * 2]     = a0;
      aux[SS + sg * 64 + cp * 2 + 1] = a1;
      __syncthreads();
      if (t < 64) {
        float v = 0;
#pragma unroll
        for (int g2 = 0; g2 < 8; ++g2) v += aux[SS + g2 * 64 + t];
        stu16(ctxb + b * HH + sl * 64 + t, f2bf(v * inv));
      }
    }
    GBAR();

    // ---- P4: layer-0 gates + GRU -> h0new ----
    gru_phase(sl, t, shmx, shmy, ctxb + b * HH, h0old + b * HH, wi0, wh0,
              gi0xb + ((size_t)td * BB + b) * H3, nullptr, bhh0,
              h0new + b * HH);
    GBAR();

    // ---- P5: layer-1 gates + GRU -> outsb[td] (= h1 state, bf16) ----
    gru_phase(sl, t, shmx, shmy, h0new + b * HH, h1old + b * HH, wi1, wh1,
              nullptr, bih1, bhh1, outsb + (size_t)td * BB * HH + b * HH);
    GBAR();
  }
#undef GBAR
}

// ---------------------------------------------------------------------------
extern "C" void kernel_launch(void* const* d_in, const int* in_sizes, int n_in,
                              void* d_out, int out_size, void* d_ws,
                              size_t ws_size, hipStream_t stream) {
  const int*   X    = (const int*)  d_in[0];
  const float* enc  = (const float*)d_in[1];
  const float* hid  = (const float*)d_in[2];
  const int*   vlen = (const int*)  d_in[3];
  const float* emb  = (const float*)d_in[4];
  const float* Wq   = (const float*)d_in[5];
  const float* Wk   = (const float*)d_in[6];
  const float* wv   = (const float*)d_in[7];
  const float* Wih0 = (const float*)d_in[8];
  const float* Whh0 = (const float*)d_in[9];
  const float* bih0 = (const float*)d_in[10];
  const float* bhh0 = (const float*)d_in[11];
  const float* Wih1 = (const float*)d_in[12];
  const float* Whh1 = (const float*)d_in[13];
  const float* bih1 = (const float*)d_in[14];
  const float* bhh1 = (const float*)d_in[15];
  const float* Wout = (const float*)d_in[16];
  const float* bout = (const float*)d_in[17];
  float* out = (float*)d_out;

  // ---- workspace (float offsets), ~70.1 MB ----
  // [0 .. 15,990,784 f) dead after k_persist; woutb overlays [0..16,384,000 f).
  float* ws = (float*)d_ws;
  unsigned short* wi0b   = (unsigned short*)ws;                 // 4 gate mats
  unsigned short* wh0b   = wi0b + (size_t)3145728;
  unsigned short* wi1b   = wh0b + (size_t)3145728;
  unsigned short* wh1b   = wi1b + (size_t)3145728;
  unsigned short* wqb    = (unsigned short*)(ws + 6291456);
  unsigned short* gi0xb  = (unsigned short*)(ws + 6815744);
  unsigned short* keysb  = (unsigned short*)(ws + 9961472);
  unsigned short* encb   = (unsigned short*)(ws + 12058624);
  unsigned short* xsb    = (unsigned short*)(ws + 14155776);    // 2MB
  unsigned short* wkb    = (unsigned short*)(ws + 14680064);    // 2MB
  unsigned short* wih0xb = (unsigned short*)(ws + 15204352);    // 3MB
  unsigned short* woutb  = (unsigned short*)ws;                 // overlay
  unsigned short* outsb  = (unsigned short*)(ws + 16384000);
  unsigned short* h0A    = (unsigned short*)(ws + 17432576);
  unsigned short* h0B    = (unsigned short*)(ws + 17448960);
  unsigned short* h1i    = (unsigned short*)(ws + 17465344);
  unsigned short* ctxb   = (unsigned short*)(ws + 17481728);
  unsigned short* qrowb  = (unsigned short*)(ws + 17498112);
  float*          scores = ws + 17514496;
  unsigned*       bar    = (unsigned*)(ws + 17518592);          // 576 u32

  k_init<<<259, 256, 0, stream>>>(hid, h0A, h1i, bar);
  k_gather<<<1024, 256, 0, stream>>>(X, emb, xsb);
  // bf16 converts for prologue GEMMs
  k_conv<<<4096, 256, 0, stream>>>(enc, encb, 256, HH);
  k_conv<<<1024, 256, 0, stream>>>(Wk, wkb, 256, HH);
  k_conv<<<3072, 256, 0, stream>>>(Wih0 + HH, wih0xb, 128, HH + EE);
  // keysb = bf16(enc @ Wk^T)   [4096,1024]x[1024,1024], MFMA
  k_gemm_mfma<<<dim3(8, 32), 256, 0, stream>>>(encb, wkb, nullptr,
                                               (float*)keysb, BB * SS, HH, HH,
                                               0, 1);
  // gi0xb = bf16(xs @ W_ih0[:,H:]^T + b_ih0)  [2048,512]x[3072,512], MFMA
  k_gemm_mfma<<<dim3(24, 16), 256, 0, stream>>>(xsb, wih0xb, bih0,
                                                (float*)gi0xb, TT * BB, H3, EE,
                                                0, 1);
  // recurrent weights -> bf16
  k_conv<<<1024, 256, 0, stream>>>(Wq, wqb, 256, HH);
  k_conv<<<3072, 256, 0, stream>>>(Wih0, wi0b, 256, HH + EE);  // ctx cols only
  k_conv<<<3072, 256, 0, stream>>>(Whh0, wh0b, 256, HH);
  k_conv<<<3072, 256, 0, stream>>>(Wih1, wi1b, 256, HH);
  k_conv<<<3072, 256, 0, stream>>>(Whh1, wh1b, 256, HH);

  // the whole 64-step recurrence, one launch, flag-barrier sync
  k_persist<<<NB, 256, 0, stream>>>(keysb, encb, gi0xb, wqb,
                                    wi0b, wh0b, wi1b, wh1b,
                                    wv, vlen, h1i,
                                    bhh0, bih1, bhh1,
                                    qrowb, scores, ctxb, h0A, h0B, outsb, bar);

  // Wout -> bf16 into the now-dead overlay, then MFMA logits GEMM
  k_conv<<<32000, 256, 0, stream>>>(Wout, woutb, 256, HH);
  k_gemm_mfma<<<dim3(250, 16), 256, 0, stream>>>(outsb, woutb, bout, out,
                                                 TT * BB, VV, HH, 1, 0);
}